// Round 6
// baseline (854.923 us; speedup 1.0000x reference)
//
#include <hip/hip_runtime.h>

#define NN_ 131072
#define E_  2097152
#define B_  64
#define K_  20480
#define H_  512
#define EPS_ 1e-6f
#define DEGSCALE 4194304.0f      // 2^22
#define DEGINV   (1.0f / 4194304.0f)
#define NKC 128                  // fc1 K-split chunks (R6: 64->128 for 4 blocks/CU)
#define CHUNK 160                // K_ / NKC
#define ITS 5                    // CHUNK / 32

// ---------------- graph preprocessing ----------------
// R5: deg+cnt fused into ONE 64-bit atomic per edge. deg fixed-point Q.22 low
// word, count high word; max row-degree*2^22 << 2^32 so no carry.
// R6: 8-way sharded histogram (shard = blockIdx&7 ~ XCD) to cut cross-XCD
// atomic line ping-pong; k_dinv reduces the 8 shards.

__global__ __launch_bounds__(256) void k_deg_hist(const int* __restrict__ ei, const float* __restrict__ ew,
                                                  unsigned long long* __restrict__ pack8) {
  int e = blockIdx.x * 256 + threadIdx.x;
  if (e >= E_) return;
  int r = ei[e];
  unsigned long long q = (unsigned long long)(unsigned)(ew[e] * DEGSCALE + 0.5f);
  atomicAdd(&pack8[(size_t)(blockIdx.x & 7) * NN_ + r], (1ULL << 32) | q);
}

__global__ __launch_bounds__(256) void k_dinv(const unsigned long long* __restrict__ pack8,
                                              float* __restrict__ dinv, int* __restrict__ cnt) {
  int n = blockIdx.x * 256 + threadIdx.x;
  if (n >= NN_) return;
  unsigned long long p = 0;
#pragma unroll
  for (int s = 0; s < 8; s++) p += pack8[(size_t)s * NN_ + n];
  float d = (float)(unsigned)(p & 0xFFFFFFFFULL) * DEGINV;
  dinv[n] = (d > 0.f) ? rsqrtf(d + EPS_) : 0.f;
  cnt[n] = (int)(p >> 32);
}

__global__ __launch_bounds__(256) void k_scan_a(const int* __restrict__ cnt, int* __restrict__ bsum) {
  __shared__ int s[256];
  int t = threadIdx.x, b = blockIdx.x;
  s[t] = cnt[b * 512 + t] + cnt[b * 512 + 256 + t];
  __syncthreads();
  for (int off = 128; off > 0; off >>= 1) {
    if (t < off) s[t] += s[t + off];
    __syncthreads();
  }
  if (t == 0) bsum[b] = s[0];
}

__global__ __launch_bounds__(256) void k_scan_b(const int* __restrict__ bsum, int* __restrict__ boff) {
  __shared__ int s[256];
  int t = threadIdx.x;
  int orig = bsum[t];
  s[t] = orig;
  __syncthreads();
  for (int off = 1; off < 256; off <<= 1) {
    int v = (t >= off) ? s[t - off] : 0;
    __syncthreads();
    s[t] += v;
    __syncthreads();
  }
  boff[t] = s[t] - orig;   // exclusive
}

__global__ __launch_bounds__(256) void k_scan_c(const int* __restrict__ cnt, const int* __restrict__ boff,
                                                int* __restrict__ rowstart) {
  __shared__ int s[256];
  int t = threadIdx.x, b = blockIdx.x;
  int base = b * 512;
  int c0 = cnt[base + 2 * t], c1 = cnt[base + 2 * t + 1];
  int pair = c0 + c1;
  s[t] = pair;
  __syncthreads();
  for (int off = 1; off < 256; off <<= 1) {
    int v = (t >= off) ? s[t - off] : 0;
    __syncthreads();
    s[t] += v;
    __syncthreads();
  }
  int excl = s[t] - pair + boff[b];
  rowstart[base + 2 * t] = excl;
  rowstart[base + 2 * t + 1] = excl + c0;
}

// R5: CSR record packed (col, w) -> single 8B scattered store

__global__ __launch_bounds__(256) void k_build(const int* __restrict__ ei, const float* __restrict__ ew,
                                               const float* __restrict__ dinv, const int* __restrict__ rowstart,
                                               int* __restrict__ fill, int2* __restrict__ ecsr) {
  int e = blockIdx.x * 256 + threadIdx.x;
  if (e >= E_) return;
  int r = ei[e], c = ei[E_ + e];
  float w = ew[e] * dinv[r] * dinv[c];
  int pos = rowstart[r] + atomicAdd(&fill[r], 1);
  ecsr[pos] = make_int2(c, __float_as_int(w));
}

// ---------------- conv1 (complex 1x1 conv + ReLU) ----------------
// Y layout: [NN][20]  (0..9 real, 10..19 imag)

__global__ __launch_bounds__(256) void k_conv1(const float* __restrict__ xr, const float* __restrict__ xi,
                                               const float* __restrict__ wr_g, const float* __restrict__ wi_g,
                                               const float* __restrict__ br_g, const float* __restrict__ bi_g,
                                               float* __restrict__ Y) {
  __shared__ float wr[100], wi[100], br[10], bi[10];
  int t = threadIdx.x;
  if (t < 100) { wr[t] = wr_g[t]; wi[t] = wi_g[t]; }
  if (t < 10)  { br[t] = br_g[t]; bi[t] = bi_g[t]; }
  __syncthreads();
  int n = blockIdx.x * 256 + t;
  float xrv[10], xiv[10];
  const float2* a = (const float2*)(xr + (size_t)n * 10);
  const float2* b2 = (const float2*)(xi + (size_t)n * 10);
#pragma unroll
  for (int i = 0; i < 5; i++) {
    float2 v = a[i];  xrv[2 * i] = v.x; xrv[2 * i + 1] = v.y;
    float2 u = b2[i]; xiv[2 * i] = u.x; xiv[2 * i + 1] = u.y;
  }
  float out[20];
#pragma unroll
  for (int c = 0; c < 10; c++) {
    float ar = br[c], ai = bi[c];
#pragma unroll
    for (int tt = 0; tt < 10; tt++) {
      float wrc = wr[c * 10 + tt], wic = wi[c * 10 + tt];
      ar += xrv[tt] * wrc - xiv[tt] * wic;
      ai += xrv[tt] * wic + xiv[tt] * wrc;
    }
    out[c] = fmaxf(ar, 0.f);
    out[10 + c] = fmaxf(ai, 0.f);
  }
  float4* yp = (float4*)(Y + (size_t)n * 20);
#pragma unroll
  for (int i = 0; i < 5; i++)
    yp[i] = make_float4(out[4 * i], out[4 * i + 1], out[4 * i + 2], out[4 * i + 3]);
}

// ---------------- Laplacian pass 1: T1 = Y - S(Y) ----------------

__global__ __launch_bounds__(256) void k_lap1(const float* __restrict__ Y, const int2* __restrict__ ecsr,
                                              const int* __restrict__ rowstart,
                                              const int* __restrict__ cnt, float* __restrict__ T1) {
  int n = blockIdx.x * 256 + threadIdx.x;
  float acc[20];
#pragma unroll
  for (int j = 0; j < 20; j++) acc[j] = 0.f;
  int e0 = rowstart[n], ec = cnt[n];
  for (int i = 0; i < ec; i++) {
    int2 rec = ecsr[e0 + i];
    int c = rec.x;
    float w = __int_as_float(rec.y);
    const float4* yp = (const float4*)(Y + (size_t)c * 20);
#pragma unroll
    for (int q = 0; q < 5; q++) {
      float4 v = yp[q];
      acc[4 * q]     += w * v.x;
      acc[4 * q + 1] += w * v.y;
      acc[4 * q + 2] += w * v.z;
      acc[4 * q + 3] += w * v.w;
    }
  }
  const float4* yn = (const float4*)(Y + (size_t)n * 20);
  float4* tp = (float4*)(T1 + (size_t)n * 20);
#pragma unroll
  for (int q = 0; q < 5; q++) {
    float4 v = yn[q];
    tp[q] = make_float4(v.x - acc[4 * q], v.y - acc[4 * q + 1],
                        v.z - acc[4 * q + 2], v.w - acc[4 * q + 3]);
  }
}

// ---------------- Laplacian pass 2 + Chebyshev combine + ReLU ----------------

__global__ __launch_bounds__(256) void k_lap2cheb(const float* __restrict__ Y, const float* __restrict__ T1,
                                                  const int2* __restrict__ ecsr,
                                                  const int* __restrict__ rowstart, const int* __restrict__ cnt,
                                                  const float* __restrict__ cw_g, const float* __restrict__ cb_g,
                                                  float* __restrict__ zr, float* __restrict__ zi) {
  __shared__ float cw[300], cb[10];
  int t = threadIdx.x;
  for (int j = t; j < 300; j += 256) cw[j] = cw_g[j];
  if (t < 10)  cb[t] = cb_g[t];
  __syncthreads();
  int n = blockIdx.x * 256 + t;
  float acc[20];
#pragma unroll
  for (int j = 0; j < 20; j++) acc[j] = 0.f;
  int e0 = rowstart[n], ec = cnt[n];
  for (int i = 0; i < ec; i++) {
    int2 rec = ecsr[e0 + i];
    int c = rec.x;
    float w = __int_as_float(rec.y);
    const float4* tp = (const float4*)(T1 + (size_t)c * 20);
#pragma unroll
    for (int q = 0; q < 5; q++) {
      float4 v = tp[q];
      acc[4 * q]     += w * v.x;
      acc[4 * q + 1] += w * v.y;
      acc[4 * q + 2] += w * v.z;
      acc[4 * q + 3] += w * v.w;
    }
  }
  float t0[20], t1v[20], t2[20];
  const float4* yn = (const float4*)(Y + (size_t)n * 20);
  const float4* tn = (const float4*)(T1 + (size_t)n * 20);
#pragma unroll
  for (int q = 0; q < 5; q++) {
    float4 v = yn[q]; t0[4 * q] = v.x; t0[4 * q + 1] = v.y; t0[4 * q + 2] = v.z; t0[4 * q + 3] = v.w;
    float4 u = tn[q]; t1v[4 * q] = u.x; t1v[4 * q + 1] = u.y; t1v[4 * q + 2] = u.z; t1v[4 * q + 3] = u.w;
  }
#pragma unroll
  for (int j = 0; j < 20; j++) t2[j] = 2.f * (t1v[j] - acc[j]) - t0[j];

  float outr[10], outi[10];
#pragma unroll
  for (int o = 0; o < 10; o++) { outr[o] = cb[o]; outi[o] = 0.f; }
#pragma unroll
  for (int i = 0; i < 10; i++) {
#pragma unroll
    for (int o = 0; o < 10; o++) {
      float w0 = cw[i * 10 + o], w1 = cw[100 + i * 10 + o], w2 = cw[200 + i * 10 + o];
      outr[o] += t0[i] * w0 + t1v[i] * w1 + t2[i] * w2;
      outi[o] += t0[10 + i] * w0 + t1v[10 + i] * w1 + t2[10 + i] * w2;
    }
  }
  float2* zrp = (float2*)(zr + (size_t)n * 10);
  float2* zip = (float2*)(zi + (size_t)n * 10);
#pragma unroll
  for (int q = 0; q < 5; q++) {
    zrp[q] = make_float2(fmaxf(outr[2 * q], 0.f), fmaxf(outr[2 * q + 1], 0.f));
    zip[q] = make_float2(fmaxf(outi[2 * q], 0.f), fmaxf(outi[2 * q + 1], 0.f));
  }
}

// ---------------- fc1 complex GEMM (split-K, partials) ----------------
// R6: grid (8 h-tiles, 128 k-chunks) = 1024 blocks = 4/CU (was 2/CU, the
// overlap limiter). chunk = 160 = 5 iters of 32. pacc: [kc][b][h][2].
// R4: spill fix — unroll-1 on it/j0 loops, hh split in halves (VGPR 116).

__global__ __launch_bounds__(256, 4) void k_fc1(const float* __restrict__ zr, const float* __restrict__ zi,
                                                const float* __restrict__ Wr, const float* __restrict__ Wi,
                                                float* __restrict__ pacc) {
  __shared__ float zsr[64][36], zsi[64][36], wsr[64][36], wsi[64][36];
  int t = threadIdx.x;
  int hb = blockIdx.x;          // 0..7
  int kc = blockIdx.y;          // 0..NKC-1
  int H0 = hb * 64;
  int tx = t & 15, ty = t >> 4; // tx: h-dim, ty: b-dim (0..15)

  float ur[4][4], ui[4][4];
#pragma unroll
  for (int i = 0; i < 4; i++)
#pragma unroll
    for (int j = 0; j < 4; j++) { ur[i][j] = 0.f; ui[i][j] = 0.f; }

#pragma unroll 1
  for (int it = 0; it < ITS; it++) {
    int JJ = kc * CHUNK + it * 32;
    __syncthreads();
#pragma unroll
    for (int l = 0; l < 2; l++) {
      int f = t + l * 256;          // float4 id 0..511
      int row = f >> 3;             // 0..63
      int j4 = (f & 7) << 2;        // 0..28
      float4 vz = *(const float4*)(zr + row * K_ + JJ + j4);
      float4 vi = *(const float4*)(zi + row * K_ + JJ + j4);
      float4 vr = *(const float4*)(Wr + (H0 + row) * K_ + JJ + j4);
      float4 vw = *(const float4*)(Wi + (H0 + row) * K_ + JJ + j4);
      *(float4*)&zsr[row][j4] = vz;
      *(float4*)&zsi[row][j4] = vi;
      *(float4*)&wsr[row][j4] = vr;
      *(float4*)&wsi[row][j4] = vw;
    }
    __syncthreads();
#pragma unroll 1
    for (int j0 = 0; j0 < 32; j0 += 4) {
      float4 za[4], zb[4];
#pragma unroll
      for (int bb = 0; bb < 4; bb++) {
        za[bb] = *(const float4*)&zsr[ty + 16 * bb][j0];
        zb[bb] = *(const float4*)&zsi[ty + 16 * bb][j0];
      }
#pragma unroll
      for (int hp = 0; hp < 2; hp++) {
        int h0 = 2 * hp, h1 = 2 * hp + 1;
        float4 wa0 = *(const float4*)&wsr[tx + 16 * h0][j0];
        float4 wb0 = *(const float4*)&wsi[tx + 16 * h0][j0];
        float4 wa1 = *(const float4*)&wsr[tx + 16 * h1][j0];
        float4 wb1 = *(const float4*)&wsi[tx + 16 * h1][j0];
#pragma unroll
        for (int bb = 0; bb < 4; bb++) {
          float4 a = za[bb], b = zb[bb];
          ur[bb][h0] += a.x * wa0.x + a.y * wa0.y + a.z * wa0.z + a.w * wa0.w
                      - b.x * wb0.x - b.y * wb0.y - b.z * wb0.z - b.w * wb0.w;
          ui[bb][h0] += a.x * wb0.x + a.y * wb0.y + a.z * wb0.z + a.w * wb0.w
                      + b.x * wa0.x + b.y * wa0.y + b.z * wa0.z + b.w * wa0.w;
          ur[bb][h1] += a.x * wa1.x + a.y * wa1.y + a.z * wa1.z + a.w * wa1.w
                      - b.x * wb1.x - b.y * wb1.y - b.z * wb1.z - b.w * wb1.w;
          ui[bb][h1] += a.x * wb1.x + a.y * wb1.y + a.z * wb1.z + a.w * wb1.w
                      + b.x * wa1.x + b.y * wa1.y + b.z * wa1.z + b.w * wa1.w;
        }
      }
    }
  }
#pragma unroll
  for (int bb = 0; bb < 4; bb++) {
    int b = ty + 16 * bb;
#pragma unroll
    for (int hh = 0; hh < 4; hh++) {
      int h = H0 + tx + 16 * hh;
      *(float2*)&pacc[(((size_t)kc * 64 + b) * 512 + h) * 2] = make_float2(ur[bb][hh], ui[bb][hh]);
    }
  }
}

// ---------------- reduce partials + fc1 bias/ReLU + actor/critic head ----------------

__global__ __launch_bounds__(256) void k_head(const float* __restrict__ pacc,
                                              const float* __restrict__ br, const float* __restrict__ bi,
                                              const float* __restrict__ actor_w, const float* __restrict__ actor_b,
                                              const float* __restrict__ critic_w, const float* __restrict__ critic_b,
                                              float* __restrict__ out) {
  __shared__ float urs[512], uis[512];
  int b = blockIdx.x, t = threadIdx.x;
  float s0r = 0, s0i = 0, s1r = 0, s1i = 0;
  for (int kc = 0; kc < NKC; kc++) {
    float4 v = *(const float4*)&pacc[(((size_t)kc * 64 + b) * 512 + 2 * t) * 2];
    s0r += v.x; s0i += v.y; s1r += v.z; s1i += v.w;
  }
  urs[2 * t]     = fmaxf(s0r + br[2 * t], 0.f);
  uis[2 * t]     = fmaxf(s0i + bi[2 * t], 0.f);
  urs[2 * t + 1] = fmaxf(s1r + br[2 * t + 1], 0.f);
  uis[2 * t + 1] = fmaxf(s1i + bi[2 * t + 1], 0.f);
  __syncthreads();
  if (t < 33) {
    const float* w = (t < 32) ? (actor_w + t * 1024) : critic_w;
    float acc = (t < 32) ? actor_b[t] : critic_b[0];
    for (int k = 0; k < 512; k++)
      acc += urs[k] * w[k] + uis[k] * w[512 + k];
    if (t < 32) out[b * 32 + t] = acc;
    else        out[2048 + b] = acc;
  }
}

// ---------------- launch ----------------

extern "C" void kernel_launch(void* const* d_in, const int* in_sizes, int n_in,
                              void* d_out, int out_size, void* d_ws, size_t ws_size,
                              hipStream_t stream) {
  const float* xr   = (const float*)d_in[0];
  const float* xi   = (const float*)d_in[1];
  const float* ew   = (const float*)d_in[2];
  const float* c1wr = (const float*)d_in[3];
  const float* c1wi = (const float*)d_in[4];
  const float* c1br = (const float*)d_in[5];
  const float* c1bi = (const float*)d_in[6];
  const float* chw  = (const float*)d_in[7];
  const float* chb  = (const float*)d_in[8];
  const float* f1wr = (const float*)d_in[9];
  const float* f1wi = (const float*)d_in[10];
  const float* f1br = (const float*)d_in[11];
  const float* f1bi = (const float*)d_in[12];
  const float* cw   = (const float*)d_in[13];
  const float* cb   = (const float*)d_in[14];
  const float* aw   = (const float*)d_in[15];
  const float* ab   = (const float*)d_in[16];
  const int*   ei   = (const int*)d_in[17];
  float* out = (float*)d_out;

  char* ws = (char*)d_ws;
  size_t off = 0;
  auto alloc = [&](size_t bytes) { char* p = ws + off; off += (bytes + 255) & ~(size_t)255; return p; };
  int*   fill     = (int*)  alloc((size_t)NN_ * 4);   // memset 0
  int*   cnt      = (int*)  alloc((size_t)NN_ * 4);
  int*   rowstart = (int*)  alloc((size_t)NN_ * 4);
  float* dinv     = (float*)alloc((size_t)NN_ * 4);
  int*   bsum     = (int*)  alloc(1024);
  int*   boff     = (int*)  alloc(1024);
  float* zr       = (float*)alloc((size_t)NN_ * 10 * 4);
  float* zi       = (float*)alloc((size_t)NN_ * 10 * 4);
  int2*  ecsr     = (int2*) alloc((size_t)E_ * 8);    // dead after lap2cheb
  float* Y        = (float*)alloc((size_t)NN_ * 20 * 4);
  float* T1       = (float*)alloc((size_t)NN_ * 20 * 4);
  // pack8 (8 MB, dead after k_dinv) aliases Y (10.5 MB, first written by conv1 later)
  unsigned long long* pack8 = (unsigned long long*)Y;
  // pacc (NKC*64*512*2*4 = 33.5 MB, written by fc1) aliases ecsr+Y+T1 (37.8 MB, all dead by then)
  float* pacc = (float*)ecsr;

  hipMemsetAsync(pack8, 0, (size_t)8 * NN_ * 8, stream);
  hipMemsetAsync(fill, 0, (size_t)NN_ * 4, stream);

  k_deg_hist<<<E_ / 256, 256, 0, stream>>>(ei, ew, pack8);
  k_dinv<<<NN_ / 256, 256, 0, stream>>>(pack8, dinv, cnt);
  k_scan_a<<<256, 256, 0, stream>>>(cnt, bsum);
  k_scan_b<<<1, 256, 0, stream>>>(bsum, boff);
  k_scan_c<<<256, 256, 0, stream>>>(cnt, boff, rowstart);
  k_build<<<E_ / 256, 256, 0, stream>>>(ei, ew, dinv, rowstart, fill, ecsr);
  k_conv1<<<NN_ / 256, 256, 0, stream>>>(xr, xi, c1wr, c1wi, c1br, c1bi, Y);
  k_lap1<<<NN_ / 256, 256, 0, stream>>>(Y, ecsr, rowstart, cnt, T1);
  k_lap2cheb<<<NN_ / 256, 256, 0, stream>>>(Y, T1, ecsr, rowstart, cnt, chw, chb, zr, zi);
  k_fc1<<<dim3(8, NKC), 256, 0, stream>>>(zr, zi, f1wr, f1wi, pacc);
  k_head<<<B_, 256, 0, stream>>>(pacc, f1br, f1bi, aw, ab, cw, cb, out);
}

// Round 7
// 631.266 us; speedup vs baseline: 1.3543x; 1.3543x over previous
//
#include <hip/hip_runtime.h>

#define NN_ 131072
#define E_  2097152
#define B_  64
#define K_  20480
#define H_  512
#define EPS_ 1e-6f
#define DEGSCALE 4194304.0f      // 2^22
#define DEGINV   (1.0f / 4194304.0f)
#define NKC 128                  // fc1 K-split chunks
#define CHUNK 160                // K_ / NKC
#define ITS 5                    // CHUNK / 32

// ---------------- graph preprocessing ----------------
// R5: deg+cnt fused into ONE 64-bit atomic per edge. deg fixed-point Q.22 low
// word, count high word; max row-degree*2^22 << 2^32 so no carry.
// R6: 8-way sharded histogram (shard = blockIdx&7 ~ XCD) to cut cross-XCD
// atomic line ping-pong; k_dinv reduces the 8 shards.

__global__ __launch_bounds__(256) void k_deg_hist(const int* __restrict__ ei, const float* __restrict__ ew,
                                                  unsigned long long* __restrict__ pack8) {
  int e = blockIdx.x * 256 + threadIdx.x;
  if (e >= E_) return;
  int r = ei[e];
  unsigned long long q = (unsigned long long)(unsigned)(ew[e] * DEGSCALE + 0.5f);
  atomicAdd(&pack8[(size_t)(blockIdx.x & 7) * NN_ + r], (1ULL << 32) | q);
}

__global__ __launch_bounds__(256) void k_dinv(const unsigned long long* __restrict__ pack8,
                                              float* __restrict__ dinv, int* __restrict__ cnt) {
  int n = blockIdx.x * 256 + threadIdx.x;
  if (n >= NN_) return;
  unsigned long long p = 0;
#pragma unroll
  for (int s = 0; s < 8; s++) p += pack8[(size_t)s * NN_ + n];
  float d = (float)(unsigned)(p & 0xFFFFFFFFULL) * DEGINV;
  dinv[n] = (d > 0.f) ? rsqrtf(d + EPS_) : 0.f;
  cnt[n] = (int)(p >> 32);
}

__global__ __launch_bounds__(256) void k_scan_a(const int* __restrict__ cnt, int* __restrict__ bsum) {
  __shared__ int s[256];
  int t = threadIdx.x, b = blockIdx.x;
  s[t] = cnt[b * 512 + t] + cnt[b * 512 + 256 + t];
  __syncthreads();
  for (int off = 128; off > 0; off >>= 1) {
    if (t < off) s[t] += s[t + off];
    __syncthreads();
  }
  if (t == 0) bsum[b] = s[0];
}

__global__ __launch_bounds__(256) void k_scan_b(const int* __restrict__ bsum, int* __restrict__ boff) {
  __shared__ int s[256];
  int t = threadIdx.x;
  int orig = bsum[t];
  s[t] = orig;
  __syncthreads();
  for (int off = 1; off < 256; off <<= 1) {
    int v = (t >= off) ? s[t - off] : 0;
    __syncthreads();
    s[t] += v;
    __syncthreads();
  }
  boff[t] = s[t] - orig;   // exclusive
}

__global__ __launch_bounds__(256) void k_scan_c(const int* __restrict__ cnt, const int* __restrict__ boff,
                                                int* __restrict__ rowstart) {
  __shared__ int s[256];
  int t = threadIdx.x, b = blockIdx.x;
  int base = b * 512;
  int c0 = cnt[base + 2 * t], c1 = cnt[base + 2 * t + 1];
  int pair = c0 + c1;
  s[t] = pair;
  __syncthreads();
  for (int off = 1; off < 256; off <<= 1) {
    int v = (t >= off) ? s[t - off] : 0;
    __syncthreads();
    s[t] += v;
    __syncthreads();
  }
  int excl = s[t] - pair + boff[b];
  rowstart[base + 2 * t] = excl;
  rowstart[base + 2 * t + 1] = excl + c0;
}

// R5: CSR record packed (col, w) -> single 8B scattered store

__global__ __launch_bounds__(256) void k_build(const int* __restrict__ ei, const float* __restrict__ ew,
                                               const float* __restrict__ dinv, const int* __restrict__ rowstart,
                                               int* __restrict__ fill, int2* __restrict__ ecsr) {
  int e = blockIdx.x * 256 + threadIdx.x;
  if (e >= E_) return;
  int r = ei[e], c = ei[E_ + e];
  float w = ew[e] * dinv[r] * dinv[c];
  int pos = rowstart[r] + atomicAdd(&fill[r], 1);
  ecsr[pos] = make_int2(c, __float_as_int(w));
}

// ---------------- conv1 (complex 1x1 conv + ReLU) ----------------
// Y layout: [NN][20]  (0..9 real, 10..19 imag)

__global__ __launch_bounds__(256) void k_conv1(const float* __restrict__ xr, const float* __restrict__ xi,
                                               const float* __restrict__ wr_g, const float* __restrict__ wi_g,
                                               const float* __restrict__ br_g, const float* __restrict__ bi_g,
                                               float* __restrict__ Y) {
  __shared__ float wr[100], wi[100], br[10], bi[10];
  int t = threadIdx.x;
  if (t < 100) { wr[t] = wr_g[t]; wi[t] = wi_g[t]; }
  if (t < 10)  { br[t] = br_g[t]; bi[t] = bi_g[t]; }
  __syncthreads();
  int n = blockIdx.x * 256 + t;
  float xrv[10], xiv[10];
  const float2* a = (const float2*)(xr + (size_t)n * 10);
  const float2* b2 = (const float2*)(xi + (size_t)n * 10);
#pragma unroll
  for (int i = 0; i < 5; i++) {
    float2 v = a[i];  xrv[2 * i] = v.x; xrv[2 * i + 1] = v.y;
    float2 u = b2[i]; xiv[2 * i] = u.x; xiv[2 * i + 1] = u.y;
  }
  float out[20];
#pragma unroll
  for (int c = 0; c < 10; c++) {
    float ar = br[c], ai = bi[c];
#pragma unroll
    for (int tt = 0; tt < 10; tt++) {
      float wrc = wr[c * 10 + tt], wic = wi[c * 10 + tt];
      ar += xrv[tt] * wrc - xiv[tt] * wic;
      ai += xrv[tt] * wic + xiv[tt] * wrc;
    }
    out[c] = fmaxf(ar, 0.f);
    out[10 + c] = fmaxf(ai, 0.f);
  }
  float4* yp = (float4*)(Y + (size_t)n * 20);
#pragma unroll
  for (int i = 0; i < 5; i++)
    yp[i] = make_float4(out[4 * i], out[4 * i + 1], out[4 * i + 2], out[4 * i + 3]);
}

// ---------------- Laplacian pass 1: T1 = Y - S(Y) ----------------

__global__ __launch_bounds__(256) void k_lap1(const float* __restrict__ Y, const int2* __restrict__ ecsr,
                                              const int* __restrict__ rowstart,
                                              const int* __restrict__ cnt, float* __restrict__ T1) {
  int n = blockIdx.x * 256 + threadIdx.x;
  float acc[20];
#pragma unroll
  for (int j = 0; j < 20; j++) acc[j] = 0.f;
  int e0 = rowstart[n], ec = cnt[n];
  for (int i = 0; i < ec; i++) {
    int2 rec = ecsr[e0 + i];
    int c = rec.x;
    float w = __int_as_float(rec.y);
    const float4* yp = (const float4*)(Y + (size_t)c * 20);
#pragma unroll
    for (int q = 0; q < 5; q++) {
      float4 v = yp[q];
      acc[4 * q]     += w * v.x;
      acc[4 * q + 1] += w * v.y;
      acc[4 * q + 2] += w * v.z;
      acc[4 * q + 3] += w * v.w;
    }
  }
  const float4* yn = (const float4*)(Y + (size_t)n * 20);
  float4* tp = (float4*)(T1 + (size_t)n * 20);
#pragma unroll
  for (int q = 0; q < 5; q++) {
    float4 v = yn[q];
    tp[q] = make_float4(v.x - acc[4 * q], v.y - acc[4 * q + 1],
                        v.z - acc[4 * q + 2], v.w - acc[4 * q + 3]);
  }
}

// ---------------- Laplacian pass 2 + Chebyshev combine + ReLU ----------------

__global__ __launch_bounds__(256) void k_lap2cheb(const float* __restrict__ Y, const float* __restrict__ T1,
                                                  const int2* __restrict__ ecsr,
                                                  const int* __restrict__ rowstart, const int* __restrict__ cnt,
                                                  const float* __restrict__ cw_g, const float* __restrict__ cb_g,
                                                  float* __restrict__ zr, float* __restrict__ zi) {
  __shared__ float cw[300], cb[10];
  int t = threadIdx.x;
  for (int j = t; j < 300; j += 256) cw[j] = cw_g[j];
  if (t < 10)  cb[t] = cb_g[t];
  __syncthreads();
  int n = blockIdx.x * 256 + t;
  float acc[20];
#pragma unroll
  for (int j = 0; j < 20; j++) acc[j] = 0.f;
  int e0 = rowstart[n], ec = cnt[n];
  for (int i = 0; i < ec; i++) {
    int2 rec = ecsr[e0 + i];
    int c = rec.x;
    float w = __int_as_float(rec.y);
    const float4* tp = (const float4*)(T1 + (size_t)c * 20);
#pragma unroll
    for (int q = 0; q < 5; q++) {
      float4 v = tp[q];
      acc[4 * q]     += w * v.x;
      acc[4 * q + 1] += w * v.y;
      acc[4 * q + 2] += w * v.z;
      acc[4 * q + 3] += w * v.w;
    }
  }
  float t0[20], t1v[20], t2[20];
  const float4* yn = (const float4*)(Y + (size_t)n * 20);
  const float4* tn = (const float4*)(T1 + (size_t)n * 20);
#pragma unroll
  for (int q = 0; q < 5; q++) {
    float4 v = yn[q]; t0[4 * q] = v.x; t0[4 * q + 1] = v.y; t0[4 * q + 2] = v.z; t0[4 * q + 3] = v.w;
    float4 u = tn[q]; t1v[4 * q] = u.x; t1v[4 * q + 1] = u.y; t1v[4 * q + 2] = u.z; t1v[4 * q + 3] = u.w;
  }
#pragma unroll
  for (int j = 0; j < 20; j++) t2[j] = 2.f * (t1v[j] - acc[j]) - t0[j];

  float outr[10], outi[10];
#pragma unroll
  for (int o = 0; o < 10; o++) { outr[o] = cb[o]; outi[o] = 0.f; }
#pragma unroll
  for (int i = 0; i < 10; i++) {
#pragma unroll
    for (int o = 0; o < 10; o++) {
      float w0 = cw[i * 10 + o], w1 = cw[100 + i * 10 + o], w2 = cw[200 + i * 10 + o];
      outr[o] += t0[i] * w0 + t1v[i] * w1 + t2[i] * w2;
      outi[o] += t0[10 + i] * w0 + t1v[10 + i] * w1 + t2[10 + i] * w2;
    }
  }
  float2* zrp = (float2*)(zr + (size_t)n * 10);
  float2* zip = (float2*)(zi + (size_t)n * 10);
#pragma unroll
  for (int q = 0; q < 5; q++) {
    zrp[q] = make_float2(fmaxf(outr[2 * q], 0.f), fmaxf(outr[2 * q + 1], 0.f));
    zip[q] = make_float2(fmaxf(outi[2 * q], 0.f), fmaxf(outi[2 * q + 1], 0.f));
  }
}

// ---------------- fc1 complex GEMM (split-K, partials) ----------------
// R7: grid (8 h-tiles, 128 k-chunks) = 1024 blocks = 4/CU. NO launch_bounds
// min-wave hint: R6's (256,4) made the allocator squeeze to 64 VGPR -> 762 MB
// spill (354 us). VGPR 116 naturally allows 4 waves/SIMD; LDS 4x36KB fits.
// R4: spill fix — unroll-1 on it/j0 loops, hh split in halves (VGPR 116).

__global__ __launch_bounds__(256) void k_fc1(const float* __restrict__ zr, const float* __restrict__ zi,
                                             const float* __restrict__ Wr, const float* __restrict__ Wi,
                                             float* __restrict__ pacc) {
  __shared__ float zsr[64][36], zsi[64][36], wsr[64][36], wsi[64][36];
  int t = threadIdx.x;
  int hb = blockIdx.x;          // 0..7
  int kc = blockIdx.y;          // 0..NKC-1
  int H0 = hb * 64;
  int tx = t & 15, ty = t >> 4; // tx: h-dim, ty: b-dim (0..15)

  float ur[4][4], ui[4][4];
#pragma unroll
  for (int i = 0; i < 4; i++)
#pragma unroll
    for (int j = 0; j < 4; j++) { ur[i][j] = 0.f; ui[i][j] = 0.f; }

#pragma unroll 1
  for (int it = 0; it < ITS; it++) {
    int JJ = kc * CHUNK + it * 32;
    __syncthreads();
#pragma unroll
    for (int l = 0; l < 2; l++) {
      int f = t + l * 256;          // float4 id 0..511
      int row = f >> 3;             // 0..63
      int j4 = (f & 7) << 2;        // 0..28
      float4 vz = *(const float4*)(zr + row * K_ + JJ + j4);
      float4 vi = *(const float4*)(zi + row * K_ + JJ + j4);
      float4 vr = *(const float4*)(Wr + (H0 + row) * K_ + JJ + j4);
      float4 vw = *(const float4*)(Wi + (H0 + row) * K_ + JJ + j4);
      *(float4*)&zsr[row][j4] = vz;
      *(float4*)&zsi[row][j4] = vi;
      *(float4*)&wsr[row][j4] = vr;
      *(float4*)&wsi[row][j4] = vw;
    }
    __syncthreads();
#pragma unroll 1
    for (int j0 = 0; j0 < 32; j0 += 4) {
      float4 za[4], zb[4];
#pragma unroll
      for (int bb = 0; bb < 4; bb++) {
        za[bb] = *(const float4*)&zsr[ty + 16 * bb][j0];
        zb[bb] = *(const float4*)&zsi[ty + 16 * bb][j0];
      }
#pragma unroll
      for (int hp = 0; hp < 2; hp++) {
        int h0 = 2 * hp, h1 = 2 * hp + 1;
        float4 wa0 = *(const float4*)&wsr[tx + 16 * h0][j0];
        float4 wb0 = *(const float4*)&wsi[tx + 16 * h0][j0];
        float4 wa1 = *(const float4*)&wsr[tx + 16 * h1][j0];
        float4 wb1 = *(const float4*)&wsi[tx + 16 * h1][j0];
#pragma unroll
        for (int bb = 0; bb < 4; bb++) {
          float4 a = za[bb], b = zb[bb];
          ur[bb][h0] += a.x * wa0.x + a.y * wa0.y + a.z * wa0.z + a.w * wa0.w
                      - b.x * wb0.x - b.y * wb0.y - b.z * wb0.z - b.w * wb0.w;
          ui[bb][h0] += a.x * wb0.x + a.y * wb0.y + a.z * wb0.z + a.w * wb0.w
                      + b.x * wa0.x + b.y * wa0.y + b.z * wa0.z + b.w * wa0.w;
          ur[bb][h1] += a.x * wa1.x + a.y * wa1.y + a.z * wa1.z + a.w * wa1.w
                      - b.x * wb1.x - b.y * wb1.y - b.z * wb1.z - b.w * wb1.w;
          ui[bb][h1] += a.x * wb1.x + a.y * wb1.y + a.z * wb1.z + a.w * wb1.w
                      + b.x * wa1.x + b.y * wa1.y + b.z * wa1.z + b.w * wa1.w;
        }
      }
    }
  }
#pragma unroll
  for (int bb = 0; bb < 4; bb++) {
    int b = ty + 16 * bb;
#pragma unroll
    for (int hh = 0; hh < 4; hh++) {
      int h = H0 + tx + 16 * hh;
      *(float2*)&pacc[(((size_t)kc * 64 + b) * 512 + h) * 2] = make_float2(ur[bb][hh], ui[bb][hh]);
    }
  }
}

// ---------------- reduce partials + fc1 bias/ReLU + actor/critic head ----------------

__global__ __launch_bounds__(256) void k_head(const float* __restrict__ pacc,
                                              const float* __restrict__ br, const float* __restrict__ bi,
                                              const float* __restrict__ actor_w, const float* __restrict__ actor_b,
                                              const float* __restrict__ critic_w, const float* __restrict__ critic_b,
                                              float* __restrict__ out) {
  __shared__ float urs[512], uis[512];
  int b = blockIdx.x, t = threadIdx.x;
  float s0r = 0, s0i = 0, s1r = 0, s1i = 0;
  for (int kc = 0; kc < NKC; kc++) {
    float4 v = *(const float4*)&pacc[(((size_t)kc * 64 + b) * 512 + 2 * t) * 2];
    s0r += v.x; s0i += v.y; s1r += v.z; s1i += v.w;
  }
  urs[2 * t]     = fmaxf(s0r + br[2 * t], 0.f);
  uis[2 * t]     = fmaxf(s0i + bi[2 * t], 0.f);
  urs[2 * t + 1] = fmaxf(s1r + br[2 * t + 1], 0.f);
  uis[2 * t + 1] = fmaxf(s1i + bi[2 * t + 1], 0.f);
  __syncthreads();
  if (t < 33) {
    const float* w = (t < 32) ? (actor_w + t * 1024) : critic_w;
    float acc = (t < 32) ? actor_b[t] : critic_b[0];
    for (int k = 0; k < 512; k++)
      acc += urs[k] * w[k] + uis[k] * w[512 + k];
    if (t < 32) out[b * 32 + t] = acc;
    else        out[2048 + b] = acc;
  }
}

// ---------------- launch ----------------

extern "C" void kernel_launch(void* const* d_in, const int* in_sizes, int n_in,
                              void* d_out, int out_size, void* d_ws, size_t ws_size,
                              hipStream_t stream) {
  const float* xr   = (const float*)d_in[0];
  const float* xi   = (const float*)d_in[1];
  const float* ew   = (const float*)d_in[2];
  const float* c1wr = (const float*)d_in[3];
  const float* c1wi = (const float*)d_in[4];
  const float* c1br = (const float*)d_in[5];
  const float* c1bi = (const float*)d_in[6];
  const float* chw  = (const float*)d_in[7];
  const float* chb  = (const float*)d_in[8];
  const float* f1wr = (const float*)d_in[9];
  const float* f1wi = (const float*)d_in[10];
  const float* f1br = (const float*)d_in[11];
  const float* f1bi = (const float*)d_in[12];
  const float* cw   = (const float*)d_in[13];
  const float* cb   = (const float*)d_in[14];
  const float* aw   = (const float*)d_in[15];
  const float* ab   = (const float*)d_in[16];
  const int*   ei   = (const int*)d_in[17];
  float* out = (float*)d_out;

  char* ws = (char*)d_ws;
  size_t off = 0;
  auto alloc = [&](size_t bytes) { char* p = ws + off; off += (bytes + 255) & ~(size_t)255; return p; };
  int*   fill     = (int*)  alloc((size_t)NN_ * 4);   // memset 0
  int*   cnt      = (int*)  alloc((size_t)NN_ * 4);
  int*   rowstart = (int*)  alloc((size_t)NN_ * 4);
  float* dinv     = (float*)alloc((size_t)NN_ * 4);
  int*   bsum     = (int*)  alloc(1024);
  int*   boff     = (int*)  alloc(1024);
  float* zr       = (float*)alloc((size_t)NN_ * 10 * 4);
  float* zi       = (float*)alloc((size_t)NN_ * 10 * 4);
  int2*  ecsr     = (int2*) alloc((size_t)E_ * 8);    // dead after lap2cheb
  float* Y        = (float*)alloc((size_t)NN_ * 20 * 4);
  float* T1       = (float*)alloc((size_t)NN_ * 20 * 4);
  // pack8 (8 MB, dead after k_dinv) aliases Y (10.5 MB, first written by conv1 later)
  unsigned long long* pack8 = (unsigned long long*)Y;
  // pacc (NKC*64*512*2*4 = 33.5 MB, written by fc1) aliases ecsr+Y+T1 (37.8 MB, all dead by then)
  float* pacc = (float*)ecsr;

  hipMemsetAsync(pack8, 0, (size_t)8 * NN_ * 8, stream);
  hipMemsetAsync(fill, 0, (size_t)NN_ * 4, stream);

  k_deg_hist<<<E_ / 256, 256, 0, stream>>>(ei, ew, pack8);
  k_dinv<<<NN_ / 256, 256, 0, stream>>>(pack8, dinv, cnt);
  k_scan_a<<<256, 256, 0, stream>>>(cnt, bsum);
  k_scan_b<<<1, 256, 0, stream>>>(bsum, boff);
  k_scan_c<<<256, 256, 0, stream>>>(cnt, boff, rowstart);
  k_build<<<E_ / 256, 256, 0, stream>>>(ei, ew, dinv, rowstart, fill, ecsr);
  k_conv1<<<NN_ / 256, 256, 0, stream>>>(xr, xi, c1wr, c1wi, c1br, c1bi, Y);
  k_lap1<<<NN_ / 256, 256, 0, stream>>>(Y, ecsr, rowstart, cnt, T1);
  k_lap2cheb<<<NN_ / 256, 256, 0, stream>>>(Y, T1, ecsr, rowstart, cnt, chw, chb, zr, zi);
  k_fc1<<<dim3(8, NKC), 256, 0, stream>>>(zr, zi, f1wr, f1wi, pacc);
  k_head<<<B_, 256, 0, stream>>>(pacc, f1br, f1bi, aw, ab, cw, cb, out);
}

// Round 8
// 562.019 us; speedup vs baseline: 1.5212x; 1.1232x over previous
//
#include <hip/hip_runtime.h>

#define NN_ 131072
#define E_  2097152
#define B_  64
#define K_  20480
#define H_  512
#define EPS_ 1e-6f
#define DEGSCALE 4194304.0f      // 2^22
#define DEGINV   (1.0f / 4194304.0f)
#define NKC 128                  // fc1 K-split chunks
#define CHUNK 160                // K_ / NKC
#define KSTEPS 5                 // CHUNK / 32 (MFMA k=32 per step)
#define LSTR 40                  // LDS row stride in bf16 elems (80 B: 16B-aligned, conflict-free)

typedef __attribute__((ext_vector_type(8))) short short8;   // 8 bf16 (4 VGPRs)
typedef __attribute__((ext_vector_type(4))) float f32x4;    // MFMA accumulator

// ---------------- graph preprocessing ----------------
// R5: deg+cnt fused into ONE 64-bit atomic per edge (Q.22 fixed-point low word,
// count high word). R6: 8-way sharded histogram to cut cross-XCD ping-pong.

__global__ __launch_bounds__(256) void k_deg_hist(const int* __restrict__ ei, const float* __restrict__ ew,
                                                  unsigned long long* __restrict__ pack8) {
  int e = blockIdx.x * 256 + threadIdx.x;
  if (e >= E_) return;
  int r = ei[e];
  unsigned long long q = (unsigned long long)(unsigned)(ew[e] * DEGSCALE + 0.5f);
  atomicAdd(&pack8[(size_t)(blockIdx.x & 7) * NN_ + r], (1ULL << 32) | q);
}

__global__ __launch_bounds__(256) void k_dinv(const unsigned long long* __restrict__ pack8,
                                              float* __restrict__ dinv, int* __restrict__ cnt) {
  int n = blockIdx.x * 256 + threadIdx.x;
  if (n >= NN_) return;
  unsigned long long p = 0;
#pragma unroll
  for (int s = 0; s < 8; s++) p += pack8[(size_t)s * NN_ + n];
  float d = (float)(unsigned)(p & 0xFFFFFFFFULL) * DEGINV;
  dinv[n] = (d > 0.f) ? rsqrtf(d + EPS_) : 0.f;
  cnt[n] = (int)(p >> 32);
}

__global__ __launch_bounds__(256) void k_scan_a(const int* __restrict__ cnt, int* __restrict__ bsum) {
  __shared__ int s[256];
  int t = threadIdx.x, b = blockIdx.x;
  s[t] = cnt[b * 512 + t] + cnt[b * 512 + 256 + t];
  __syncthreads();
  for (int off = 128; off > 0; off >>= 1) {
    if (t < off) s[t] += s[t + off];
    __syncthreads();
  }
  if (t == 0) bsum[b] = s[0];
}

__global__ __launch_bounds__(256) void k_scan_b(const int* __restrict__ bsum, int* __restrict__ boff) {
  __shared__ int s[256];
  int t = threadIdx.x;
  int orig = bsum[t];
  s[t] = orig;
  __syncthreads();
  for (int off = 1; off < 256; off <<= 1) {
    int v = (t >= off) ? s[t - off] : 0;
    __syncthreads();
    s[t] += v;
    __syncthreads();
  }
  boff[t] = s[t] - orig;   // exclusive
}

__global__ __launch_bounds__(256) void k_scan_c(const int* __restrict__ cnt, const int* __restrict__ boff,
                                                int* __restrict__ rowstart) {
  __shared__ int s[256];
  int t = threadIdx.x, b = blockIdx.x;
  int base = b * 512;
  int c0 = cnt[base + 2 * t], c1 = cnt[base + 2 * t + 1];
  int pair = c0 + c1;
  s[t] = pair;
  __syncthreads();
  for (int off = 1; off < 256; off <<= 1) {
    int v = (t >= off) ? s[t - off] : 0;
    __syncthreads();
    s[t] += v;
    __syncthreads();
  }
  int excl = s[t] - pair + boff[b];
  rowstart[base + 2 * t] = excl;
  rowstart[base + 2 * t + 1] = excl + c0;
}

// R5: CSR record packed (col, w) -> single 8B scattered store

__global__ __launch_bounds__(256) void k_build(const int* __restrict__ ei, const float* __restrict__ ew,
                                               const float* __restrict__ dinv, const int* __restrict__ rowstart,
                                               int* __restrict__ fill, int2* __restrict__ ecsr) {
  int e = blockIdx.x * 256 + threadIdx.x;
  if (e >= E_) return;
  int r = ei[e], c = ei[E_ + e];
  float w = ew[e] * dinv[r] * dinv[c];
  int pos = rowstart[r] + atomicAdd(&fill[r], 1);
  ecsr[pos] = make_int2(c, __float_as_int(w));
}

// ---------------- conv1 (complex 1x1 conv + ReLU) ----------------
// Y layout: [NN][20]  (0..9 real, 10..19 imag)

__global__ __launch_bounds__(256) void k_conv1(const float* __restrict__ xr, const float* __restrict__ xi,
                                               const float* __restrict__ wr_g, const float* __restrict__ wi_g,
                                               const float* __restrict__ br_g, const float* __restrict__ bi_g,
                                               float* __restrict__ Y) {
  __shared__ float wr[100], wi[100], br[10], bi[10];
  int t = threadIdx.x;
  if (t < 100) { wr[t] = wr_g[t]; wi[t] = wi_g[t]; }
  if (t < 10)  { br[t] = br_g[t]; bi[t] = bi_g[t]; }
  __syncthreads();
  int n = blockIdx.x * 256 + t;
  float xrv[10], xiv[10];
  const float2* a = (const float2*)(xr + (size_t)n * 10);
  const float2* b2 = (const float2*)(xi + (size_t)n * 10);
#pragma unroll
  for (int i = 0; i < 5; i++) {
    float2 v = a[i];  xrv[2 * i] = v.x; xrv[2 * i + 1] = v.y;
    float2 u = b2[i]; xiv[2 * i] = u.x; xiv[2 * i + 1] = u.y;
  }
  float out[20];
#pragma unroll
  for (int c = 0; c < 10; c++) {
    float ar = br[c], ai = bi[c];
#pragma unroll
    for (int tt = 0; tt < 10; tt++) {
      float wrc = wr[c * 10 + tt], wic = wi[c * 10 + tt];
      ar += xrv[tt] * wrc - xiv[tt] * wic;
      ai += xrv[tt] * wic + xiv[tt] * wrc;
    }
    out[c] = fmaxf(ar, 0.f);
    out[10 + c] = fmaxf(ai, 0.f);
  }
  float4* yp = (float4*)(Y + (size_t)n * 20);
#pragma unroll
  for (int i = 0; i < 5; i++)
    yp[i] = make_float4(out[4 * i], out[4 * i + 1], out[4 * i + 2], out[4 * i + 3]);
}

// ---------------- Laplacian pass 1: T1 = Y - S(Y) ----------------

__global__ __launch_bounds__(256) void k_lap1(const float* __restrict__ Y, const int2* __restrict__ ecsr,
                                              const int* __restrict__ rowstart,
                                              const int* __restrict__ cnt, float* __restrict__ T1) {
  int n = blockIdx.x * 256 + threadIdx.x;
  float acc[20];
#pragma unroll
  for (int j = 0; j < 20; j++) acc[j] = 0.f;
  int e0 = rowstart[n], ec = cnt[n];
  for (int i = 0; i < ec; i++) {
    int2 rec = ecsr[e0 + i];
    int c = rec.x;
    float w = __int_as_float(rec.y);
    const float4* yp = (const float4*)(Y + (size_t)c * 20);
#pragma unroll
    for (int q = 0; q < 5; q++) {
      float4 v = yp[q];
      acc[4 * q]     += w * v.x;
      acc[4 * q + 1] += w * v.y;
      acc[4 * q + 2] += w * v.z;
      acc[4 * q + 3] += w * v.w;
    }
  }
  const float4* yn = (const float4*)(Y + (size_t)n * 20);
  float4* tp = (float4*)(T1 + (size_t)n * 20);
#pragma unroll
  for (int q = 0; q < 5; q++) {
    float4 v = yn[q];
    tp[q] = make_float4(v.x - acc[4 * q], v.y - acc[4 * q + 1],
                        v.z - acc[4 * q + 2], v.w - acc[4 * q + 3]);
  }
}

// ---------------- Laplacian pass 2 + Chebyshev combine + ReLU ----------------

__global__ __launch_bounds__(256) void k_lap2cheb(const float* __restrict__ Y, const float* __restrict__ T1,
                                                  const int2* __restrict__ ecsr,
                                                  const int* __restrict__ rowstart, const int* __restrict__ cnt,
                                                  const float* __restrict__ cw_g, const float* __restrict__ cb_g,
                                                  float* __restrict__ zr, float* __restrict__ zi) {
  __shared__ float cw[300], cb[10];
  int t = threadIdx.x;
  for (int j = t; j < 300; j += 256) cw[j] = cw_g[j];
  if (t < 10)  cb[t] = cb_g[t];
  __syncthreads();
  int n = blockIdx.x * 256 + t;
  float acc[20];
#pragma unroll
  for (int j = 0; j < 20; j++) acc[j] = 0.f;
  int e0 = rowstart[n], ec = cnt[n];
  for (int i = 0; i < ec; i++) {
    int2 rec = ecsr[e0 + i];
    int c = rec.x;
    float w = __int_as_float(rec.y);
    const float4* tp = (const float4*)(T1 + (size_t)c * 20);
#pragma unroll
    for (int q = 0; q < 5; q++) {
      float4 v = tp[q];
      acc[4 * q]     += w * v.x;
      acc[4 * q + 1] += w * v.y;
      acc[4 * q + 2] += w * v.z;
      acc[4 * q + 3] += w * v.w;
    }
  }
  float t0[20], t1v[20], t2[20];
  const float4* yn = (const float4*)(Y + (size_t)n * 20);
  const float4* tn = (const float4*)(T1 + (size_t)n * 20);
#pragma unroll
  for (int q = 0; q < 5; q++) {
    float4 v = yn[q]; t0[4 * q] = v.x; t0[4 * q + 1] = v.y; t0[4 * q + 2] = v.z; t0[4 * q + 3] = v.w;
    float4 u = tn[q]; t1v[4 * q] = u.x; t1v[4 * q + 1] = u.y; t1v[4 * q + 2] = u.z; t1v[4 * q + 3] = u.w;
  }
#pragma unroll
  for (int j = 0; j < 20; j++) t2[j] = 2.f * (t1v[j] - acc[j]) - t0[j];

  float outr[10], outi[10];
#pragma unroll
  for (int o = 0; o < 10; o++) { outr[o] = cb[o]; outi[o] = 0.f; }
#pragma unroll
  for (int i = 0; i < 10; i++) {
#pragma unroll
    for (int o = 0; o < 10; o++) {
      float w0 = cw[i * 10 + o], w1 = cw[100 + i * 10 + o], w2 = cw[200 + i * 10 + o];
      outr[o] += t0[i] * w0 + t1v[i] * w1 + t2[i] * w2;
      outi[o] += t0[10 + i] * w0 + t1v[10 + i] * w1 + t2[10 + i] * w2;
    }
  }
  float2* zrp = (float2*)(zr + (size_t)n * 10);
  float2* zip = (float2*)(zi + (size_t)n * 10);
#pragma unroll
  for (int q = 0; q < 5; q++) {
    zrp[q] = make_float2(fmaxf(outr[2 * q], 0.f), fmaxf(outr[2 * q + 1], 0.f));
    zip[q] = make_float2(fmaxf(outi[2 * q], 0.f), fmaxf(outi[2 * q + 1], 0.f));
  }
}

// ---------------- fc1 complex GEMM: split-bf16 MFMA ----------------
// R8: fp32 VALU GEMM (132 us, 4x the 34 us FMA floor, grid-insensitive) ->
// mfma_f32_16x16x32_bf16 with hi/lo split-bf16 (3 MFMAs per real product,
// rel err ~1e-5). Staging converts fp32->bf16 hi/lo in the VGPR round-trip;
// weights still read exactly once (84 MB = 13.4 us HBM floor).
// LDS: 8 arrays [64][LSTR=40] bf16 = 40 KB -> 4 blocks/CU.
// Wave layout: wave wv owns h-strip wv*16..+15 (B-frag), 4 m-tiles of b.
// Frag maps (m89/m120-verified): A/B lane L: row L&15, k (L>>4)*8+j;
// D lane L reg i: row (L>>4)*4+i, col L&15.

__device__ __forceinline__ void cvt_hilo(float f, unsigned& h, unsigned& l) {
  unsigned u = __float_as_uint(f);
  h = (u + 0x7FFFu + ((u >> 16) & 1u)) >> 16;          // RNE to bf16
  float lf = f - __uint_as_float(h << 16);
  unsigned ul = __float_as_uint(lf);
  l = (ul + 0x7FFFu + ((ul >> 16) & 1u)) >> 16;
}

#define LIDX(a, r, c) (((a) * 64 + (r)) * LSTR + (c))

__global__ __launch_bounds__(256) void k_fc1(const float* __restrict__ zr, const float* __restrict__ zi,
                                             const float* __restrict__ Wr, const float* __restrict__ Wi,
                                             float* __restrict__ pacc) {
  __shared__ unsigned short ls[8 * 64 * LSTR];   // 0 zrh,1 zrl,2 zih,3 zil,4 wrh,5 wrl,6 wih,7 wil
  int t = threadIdx.x;
  int hb = blockIdx.x;          // 0..7
  int kc = blockIdx.y;          // 0..NKC-1
  int H0 = hb * 64;
  int lane = t & 63, wv = t >> 6;
  int m = lane & 15, q = lane >> 4;

  f32x4 p1[4], p2[4], p3[4], p4[4];
  f32x4 zero4 = {0.f, 0.f, 0.f, 0.f};
#pragma unroll
  for (int i = 0; i < 4; i++) { p1[i] = zero4; p2[i] = zero4; p3[i] = zero4; p4[i] = zero4; }

#pragma unroll 1
  for (int ks = 0; ks < KSTEPS; ks++) {
    int k0 = kc * CHUNK + ks * 32;
    __syncthreads();
    // stage + convert: 2048 float4 tasks over 256 threads
#pragma unroll
    for (int p = 0; p < 8; p++) {
      int tau = t + (p << 8);
      int arr = tau >> 9;             // 0 zr, 1 zi, 2 Wr, 3 Wi
      int row = (tau >> 3) & 63;
      int grp = tau & 7;
      const float* base = (arr == 0) ? (zr + (size_t)row * K_)
                        : (arr == 1) ? (zi + (size_t)row * K_)
                        : (arr == 2) ? (Wr + (size_t)(H0 + row) * K_)
                                     : (Wi + (size_t)(H0 + row) * K_);
      float4 v = *(const float4*)(base + k0 + grp * 4);
      unsigned h0, l0, h1, l1, h2, l2, h3, l3;
      cvt_hilo(v.x, h0, l0); cvt_hilo(v.y, h1, l1);
      cvt_hilo(v.z, h2, l2); cvt_hilo(v.w, h3, l3);
      *(uint2*)&ls[LIDX(arr * 2,     row, grp * 4)] = make_uint2(h0 | (h1 << 16), h2 | (h3 << 16));
      *(uint2*)&ls[LIDX(arr * 2 + 1, row, grp * 4)] = make_uint2(l0 | (l1 << 16), l2 | (l3 << 16));
    }
    __syncthreads();

    short8 bwrh = *(const short8*)&ls[LIDX(4, wv * 16 + m, q * 8)];
    short8 bwrl = *(const short8*)&ls[LIDX(5, wv * 16 + m, q * 8)];
    short8 bwih = *(const short8*)&ls[LIDX(6, wv * 16 + m, q * 8)];
    short8 bwil = *(const short8*)&ls[LIDX(7, wv * 16 + m, q * 8)];
#pragma unroll
    for (int mt = 0; mt < 4; mt++) {
      short8 azrh = *(const short8*)&ls[LIDX(0, mt * 16 + m, q * 8)];
      short8 azrl = *(const short8*)&ls[LIDX(1, mt * 16 + m, q * 8)];
      short8 azih = *(const short8*)&ls[LIDX(2, mt * 16 + m, q * 8)];
      short8 azil = *(const short8*)&ls[LIDX(3, mt * 16 + m, q * 8)];
      p1[mt] = __builtin_amdgcn_mfma_f32_16x16x32_bf16(azrh, bwrh, p1[mt], 0, 0, 0);
      p2[mt] = __builtin_amdgcn_mfma_f32_16x16x32_bf16(azih, bwih, p2[mt], 0, 0, 0);
      p3[mt] = __builtin_amdgcn_mfma_f32_16x16x32_bf16(azrh, bwih, p3[mt], 0, 0, 0);
      p4[mt] = __builtin_amdgcn_mfma_f32_16x16x32_bf16(azih, bwrh, p4[mt], 0, 0, 0);
      p1[mt] = __builtin_amdgcn_mfma_f32_16x16x32_bf16(azrh, bwrl, p1[mt], 0, 0, 0);
      p2[mt] = __builtin_amdgcn_mfma_f32_16x16x32_bf16(azih, bwil, p2[mt], 0, 0, 0);
      p3[mt] = __builtin_amdgcn_mfma_f32_16x16x32_bf16(azrh, bwil, p3[mt], 0, 0, 0);
      p4[mt] = __builtin_amdgcn_mfma_f32_16x16x32_bf16(azih, bwrl, p4[mt], 0, 0, 0);
      p1[mt] = __builtin_amdgcn_mfma_f32_16x16x32_bf16(azrl, bwrh, p1[mt], 0, 0, 0);
      p2[mt] = __builtin_amdgcn_mfma_f32_16x16x32_bf16(azil, bwih, p2[mt], 0, 0, 0);
      p3[mt] = __builtin_amdgcn_mfma_f32_16x16x32_bf16(azrl, bwih, p3[mt], 0, 0, 0);
      p4[mt] = __builtin_amdgcn_mfma_f32_16x16x32_bf16(azil, bwrh, p4[mt], 0, 0, 0);
    }
  }

  // epilogue: ur = P1 - P2, ui = P3 + P4; D lane map row=(q*4+i), col=m
#pragma unroll
  for (int mt = 0; mt < 4; mt++) {
#pragma unroll
    for (int i = 0; i < 4; i++) {
      int b = mt * 16 + q * 4 + i;
      int h = H0 + wv * 16 + m;
      *(float2*)&pacc[(((size_t)kc * 64 + b) * 512 + h) * 2] =
          make_float2(p1[mt][i] - p2[mt][i], p3[mt][i] + p4[mt][i]);
    }
  }
}

// ---------------- reduce partials + fc1 bias/ReLU + actor/critic head ----------------

__global__ __launch_bounds__(256) void k_head(const float* __restrict__ pacc,
                                              const float* __restrict__ br, const float* __restrict__ bi,
                                              const float* __restrict__ actor_w, const float* __restrict__ actor_b,
                                              const float* __restrict__ critic_w, const float* __restrict__ critic_b,
                                              float* __restrict__ out) {
  __shared__ float urs[512], uis[512];
  int b = blockIdx.x, t = threadIdx.x;
  float s0r = 0, s0i = 0, s1r = 0, s1i = 0;
  for (int kc = 0; kc < NKC; kc++) {
    float4 v = *(const float4*)&pacc[(((size_t)kc * 64 + b) * 512 + 2 * t) * 2];
    s0r += v.x; s0i += v.y; s1r += v.z; s1i += v.w;
  }
  urs[2 * t]     = fmaxf(s0r + br[2 * t], 0.f);
  uis[2 * t]     = fmaxf(s0i + bi[2 * t], 0.f);
  urs[2 * t + 1] = fmaxf(s1r + br[2 * t + 1], 0.f);
  uis[2 * t + 1] = fmaxf(s1i + bi[2 * t + 1], 0.f);
  __syncthreads();
  if (t < 33) {
    const float* w = (t < 32) ? (actor_w + t * 1024) : critic_w;
    float acc = (t < 32) ? actor_b[t] : critic_b[0];
    for (int k = 0; k < 512; k++)
      acc += urs[k] * w[k] + uis[k] * w[512 + k];
    if (t < 32) out[b * 32 + t] = acc;
    else        out[2048 + b] = acc;
  }
}

// ---------------- launch ----------------

extern "C" void kernel_launch(void* const* d_in, const int* in_sizes, int n_in,
                              void* d_out, int out_size, void* d_ws, size_t ws_size,
                              hipStream_t stream) {
  const float* xr   = (const float*)d_in[0];
  const float* xi   = (const float*)d_in[1];
  const float* ew   = (const float*)d_in[2];
  const float* c1wr = (const float*)d_in[3];
  const float* c1wi = (const float*)d_in[4];
  const float* c1br = (const float*)d_in[5];
  const float* c1bi = (const float*)d_in[6];
  const float* chw  = (const float*)d_in[7];
  const float* chb  = (const float*)d_in[8];
  const float* f1wr = (const float*)d_in[9];
  const float* f1wi = (const float*)d_in[10];
  const float* f1br = (const float*)d_in[11];
  const float* f1bi = (const float*)d_in[12];
  const float* cw   = (const float*)d_in[13];
  const float* cb   = (const float*)d_in[14];
  const float* aw   = (const float*)d_in[15];
  const float* ab   = (const float*)d_in[16];
  const int*   ei   = (const int*)d_in[17];
  float* out = (float*)d_out;

  char* ws = (char*)d_ws;
  size_t off = 0;
  auto alloc = [&](size_t bytes) { char* p = ws + off; off += (bytes + 255) & ~(size_t)255; return p; };
  int*   fill     = (int*)  alloc((size_t)NN_ * 4);   // memset 0
  int*   cnt      = (int*)  alloc((size_t)NN_ * 4);
  int*   rowstart = (int*)  alloc((size_t)NN_ * 4);
  float* dinv     = (float*)alloc((size_t)NN_ * 4);
  int*   bsum     = (int*)  alloc(1024);
  int*   boff     = (int*)  alloc(1024);
  float* zr       = (float*)alloc((size_t)NN_ * 10 * 4);
  float* zi       = (float*)alloc((size_t)NN_ * 10 * 4);
  int2*  ecsr     = (int2*) alloc((size_t)E_ * 8);    // dead after lap2cheb
  float* Y        = (float*)alloc((size_t)NN_ * 20 * 4);
  float* T1       = (float*)alloc((size_t)NN_ * 20 * 4);
  // pack8 (8 MB, dead after k_dinv) aliases Y (10.5 MB, first written by conv1 later)
  unsigned long long* pack8 = (unsigned long long*)Y;
  // pacc (NKC*64*512*2*4 = 33.5 MB, written by fc1) aliases ecsr+Y+T1 (37.8 MB, all dead by then)
  float* pacc = (float*)ecsr;

  hipMemsetAsync(pack8, 0, (size_t)8 * NN_ * 8, stream);
  hipMemsetAsync(fill, 0, (size_t)NN_ * 4, stream);

  k_deg_hist<<<E_ / 256, 256, 0, stream>>>(ei, ew, pack8);
  k_dinv<<<NN_ / 256, 256, 0, stream>>>(pack8, dinv, cnt);
  k_scan_a<<<256, 256, 0, stream>>>(cnt, bsum);
  k_scan_b<<<1, 256, 0, stream>>>(bsum, boff);
  k_scan_c<<<256, 256, 0, stream>>>(cnt, boff, rowstart);
  k_build<<<E_ / 256, 256, 0, stream>>>(ei, ew, dinv, rowstart, fill, ecsr);
  k_conv1<<<NN_ / 256, 256, 0, stream>>>(xr, xi, c1wr, c1wi, c1br, c1bi, Y);
  k_lap1<<<NN_ / 256, 256, 0, stream>>>(Y, ecsr, rowstart, cnt, T1);
  k_lap2cheb<<<NN_ / 256, 256, 0, stream>>>(Y, T1, ecsr, rowstart, cnt, chw, chb, zr, zi);
  k_fc1<<<dim3(8, NKC), 256, 0, stream>>>(zr, zi, f1wr, f1wi, pacc);
  k_head<<<B_, 256, 0, stream>>>(pacc, f1br, f1bi, aw, ab, cw, cb, out);
}

// Round 9
// 539.849 us; speedup vs baseline: 1.5836x; 1.0411x over previous
//
#include <hip/hip_runtime.h>

#define NN_ 131072
#define E_  2097152
#define B_  64
#define K_  20480
#define H_  512
#define EPS_ 1e-6f
#define DEGSCALE 4194304.0f      // 2^22
#define DEGINV   (1.0f / 4194304.0f)
#define NKC 128                  // fc1 K-split chunks
#define CHUNK 160                // K_ / NKC
#define KSTEPS 5                 // CHUNK / 32 (MFMA k=32 per step)
#define LSTR 40                  // fc1 LDS row stride in bf16 elems

typedef __attribute__((ext_vector_type(8))) short short8;   // 8 bf16 (4 VGPRs)
typedef __attribute__((ext_vector_type(4))) float f32x4;    // MFMA accumulator

// ---------------- graph preprocessing ----------------
// R9: zero fabric-atomic CSR build.
//  k_cnt: per-edge 64-bit atomic on pack8[real_XCD][row] with WORKGROUP scope
//   -> RMW executes in the local XCD L2 (no device write-through). Correct
//   because each shard address is only ever touched by one L2 (XCD-pinned via
//   HW_REG_XCC_ID). Returned old count = per-shard ordinal -> ord[e].
//  k_off: reduce 8 shards -> cnt, dinv (Q22 deg), per-shard offsets so[n].
//  k_build: atomic-free scatter: pos = rowstart + shard_off + ordinal.

__global__ __launch_bounds__(256) void k_cnt(const int* __restrict__ ei, const float* __restrict__ ew,
                                             unsigned long long* __restrict__ pack8,
                                             unsigned short* __restrict__ ord) {
  int e = blockIdx.x * 256 + threadIdx.x;
  if (e >= E_) return;
  int r = ei[e];
  unsigned q = (unsigned)(ew[e] * DEGSCALE + 0.5f);
  unsigned x;
  asm volatile("s_getreg_b32 %0, hwreg(HW_REG_XCC_ID)" : "=s"(x));
  x &= 7u;
  unsigned long long old = __hip_atomic_fetch_add(
      &pack8[(size_t)x * NN_ + r], (1ULL << 32) | (unsigned long long)q,
      __ATOMIC_RELAXED, __HIP_MEMORY_SCOPE_WORKGROUP);
  ord[e] = (unsigned short)((x << 13) | (unsigned)(old >> 32));   // count <= ~60 << 8191
}

__global__ __launch_bounds__(256) void k_off(const unsigned long long* __restrict__ pack8,
                                             int* __restrict__ cnt, float* __restrict__ dinv,
                                             unsigned long long* __restrict__ so) {
  int n = blockIdx.x * 256 + threadIdx.x;
  if (n >= NN_) return;
  unsigned long long deg = 0, sov = 0;
  unsigned off = 0;
#pragma unroll
  for (int s = 0; s < 8; s++) {
    unsigned long long p = pack8[(size_t)s * NN_ + n];
    sov |= (unsigned long long)(off & 0xFFu) << (8 * s);
    off += (unsigned)(p >> 32);
    deg += (p & 0xFFFFFFFFULL);
  }
  cnt[n] = (int)off;
  float d = (float)deg * DEGINV;
  dinv[n] = (d > 0.f) ? rsqrtf(d + EPS_) : 0.f;
  so[n] = sov;
}

__global__ __launch_bounds__(256) void k_scan_a(const int* __restrict__ cnt, int* __restrict__ bsum) {
  __shared__ int s[256];
  int t = threadIdx.x, b = blockIdx.x;
  s[t] = cnt[b * 512 + t] + cnt[b * 512 + 256 + t];
  __syncthreads();
  for (int off = 128; off > 0; off >>= 1) {
    if (t < off) s[t] += s[t + off];
    __syncthreads();
  }
  if (t == 0) bsum[b] = s[0];
}

__global__ __launch_bounds__(256) void k_scan_b(const int* __restrict__ bsum, int* __restrict__ boff) {
  __shared__ int s[256];
  int t = threadIdx.x;
  int orig = bsum[t];
  s[t] = orig;
  __syncthreads();
  for (int off = 1; off < 256; off <<= 1) {
    int v = (t >= off) ? s[t - off] : 0;
    __syncthreads();
    s[t] += v;
    __syncthreads();
  }
  boff[t] = s[t] - orig;   // exclusive
}

__global__ __launch_bounds__(256) void k_scan_c(const int* __restrict__ cnt, const int* __restrict__ boff,
                                                int* __restrict__ rowstart) {
  __shared__ int s[256];
  int t = threadIdx.x, b = blockIdx.x;
  int base = b * 512;
  int c0 = cnt[base + 2 * t], c1 = cnt[base + 2 * t + 1];
  int pair = c0 + c1;
  s[t] = pair;
  __syncthreads();
  for (int off = 1; off < 256; off <<= 1) {
    int v = (t >= off) ? s[t - off] : 0;
    __syncthreads();
    s[t] += v;
    __syncthreads();
  }
  int excl = s[t] - pair + boff[b];
  rowstart[base + 2 * t] = excl;
  rowstart[base + 2 * t + 1] = excl + c0;
}

// R9: atomic-free CSR scatter (position fully determined by ord + shard offset)

__global__ __launch_bounds__(256) void k_build(const int* __restrict__ ei, const float* __restrict__ ew,
                                               const float* __restrict__ dinv, const int* __restrict__ rowstart,
                                               const unsigned short* __restrict__ ord,
                                               const unsigned long long* __restrict__ so,
                                               int2* __restrict__ ecsr) {
  int e = blockIdx.x * 256 + threadIdx.x;
  if (e >= E_) return;
  int r = ei[e], c = ei[E_ + e];
  unsigned ow = ord[e];
  unsigned s = ow >> 13, o = ow & 8191u;
  int pos = rowstart[r] + (int)((so[r] >> (8 * s)) & 0xFFu) + (int)o;
  float w = ew[e] * dinv[r] * dinv[c];
  ecsr[pos] = make_int2(c, __float_as_int(w));
}

// ---------------- conv1 (complex 1x1 conv + ReLU) ----------------
// Y layout: [NN][20]  (0..9 real, 10..19 imag)

__global__ __launch_bounds__(256) void k_conv1(const float* __restrict__ xr, const float* __restrict__ xi,
                                               const float* __restrict__ wr_g, const float* __restrict__ wi_g,
                                               const float* __restrict__ br_g, const float* __restrict__ bi_g,
                                               float* __restrict__ Y) {
  __shared__ float wr[100], wi[100], br[10], bi[10];
  int t = threadIdx.x;
  if (t < 100) { wr[t] = wr_g[t]; wi[t] = wi_g[t]; }
  if (t < 10)  { br[t] = br_g[t]; bi[t] = bi_g[t]; }
  __syncthreads();
  int n = blockIdx.x * 256 + t;
  float xrv[10], xiv[10];
  const float2* a = (const float2*)(xr + (size_t)n * 10);
  const float2* b2 = (const float2*)(xi + (size_t)n * 10);
#pragma unroll
  for (int i = 0; i < 5; i++) {
    float2 v = a[i];  xrv[2 * i] = v.x; xrv[2 * i + 1] = v.y;
    float2 u = b2[i]; xiv[2 * i] = u.x; xiv[2 * i + 1] = u.y;
  }
  float out[20];
#pragma unroll
  for (int c = 0; c < 10; c++) {
    float ar = br[c], ai = bi[c];
#pragma unroll
    for (int tt = 0; tt < 10; tt++) {
      float wrc = wr[c * 10 + tt], wic = wi[c * 10 + tt];
      ar += xrv[tt] * wrc - xiv[tt] * wic;
      ai += xrv[tt] * wic + xiv[tt] * wrc;
    }
    out[c] = fmaxf(ar, 0.f);
    out[10 + c] = fmaxf(ai, 0.f);
  }
  float4* yp = (float4*)(Y + (size_t)n * 20);
#pragma unroll
  for (int i = 0; i < 5; i++)
    yp[i] = make_float4(out[4 * i], out[4 * i + 1], out[4 * i + 2], out[4 * i + 3]);
}

// ---------------- Laplacian pass 1: T1 = Y - S(Y) ----------------

__global__ __launch_bounds__(256) void k_lap1(const float* __restrict__ Y, const int2* __restrict__ ecsr,
                                              const int* __restrict__ rowstart,
                                              const int* __restrict__ cnt, float* __restrict__ T1) {
  int n = blockIdx.x * 256 + threadIdx.x;
  float acc[20];
#pragma unroll
  for (int j = 0; j < 20; j++) acc[j] = 0.f;
  int e0 = rowstart[n], ec = cnt[n];
  for (int i = 0; i < ec; i++) {
    int2 rec = ecsr[e0 + i];
    int c = rec.x;
    float w = __int_as_float(rec.y);
    const float4* yp = (const float4*)(Y + (size_t)c * 20);
#pragma unroll
    for (int q = 0; q < 5; q++) {
      float4 v = yp[q];
      acc[4 * q]     += w * v.x;
      acc[4 * q + 1] += w * v.y;
      acc[4 * q + 2] += w * v.z;
      acc[4 * q + 3] += w * v.w;
    }
  }
  const float4* yn = (const float4*)(Y + (size_t)n * 20);
  float4* tp = (float4*)(T1 + (size_t)n * 20);
#pragma unroll
  for (int q = 0; q < 5; q++) {
    float4 v = yn[q];
    tp[q] = make_float4(v.x - acc[4 * q], v.y - acc[4 * q + 1],
                        v.z - acc[4 * q + 2], v.w - acc[4 * q + 3]);
  }
}

// ---------------- Laplacian pass 2 + Chebyshev combine + ReLU ----------------

__global__ __launch_bounds__(256) void k_lap2cheb(const float* __restrict__ Y, const float* __restrict__ T1,
                                                  const int2* __restrict__ ecsr,
                                                  const int* __restrict__ rowstart, const int* __restrict__ cnt,
                                                  const float* __restrict__ cw_g, const float* __restrict__ cb_g,
                                                  float* __restrict__ zr, float* __restrict__ zi) {
  __shared__ float cw[300], cb[10];
  int t = threadIdx.x;
  for (int j = t; j < 300; j += 256) cw[j] = cw_g[j];
  if (t < 10)  cb[t] = cb_g[t];
  __syncthreads();
  int n = blockIdx.x * 256 + t;
  float acc[20];
#pragma unroll
  for (int j = 0; j < 20; j++) acc[j] = 0.f;
  int e0 = rowstart[n], ec = cnt[n];
  for (int i = 0; i < ec; i++) {
    int2 rec = ecsr[e0 + i];
    int c = rec.x;
    float w = __int_as_float(rec.y);
    const float4* tp = (const float4*)(T1 + (size_t)c * 20);
#pragma unroll
    for (int q = 0; q < 5; q++) {
      float4 v = tp[q];
      acc[4 * q]     += w * v.x;
      acc[4 * q + 1] += w * v.y;
      acc[4 * q + 2] += w * v.z;
      acc[4 * q + 3] += w * v.w;
    }
  }
  float t0[20], t1v[20], t2[20];
  const float4* yn = (const float4*)(Y + (size_t)n * 20);
  const float4* tn = (const float4*)(T1 + (size_t)n * 20);
#pragma unroll
  for (int q = 0; q < 5; q++) {
    float4 v = yn[q]; t0[4 * q] = v.x; t0[4 * q + 1] = v.y; t0[4 * q + 2] = v.z; t0[4 * q + 3] = v.w;
    float4 u = tn[q]; t1v[4 * q] = u.x; t1v[4 * q + 1] = u.y; t1v[4 * q + 2] = u.z; t1v[4 * q + 3] = u.w;
  }
#pragma unroll
  for (int j = 0; j < 20; j++) t2[j] = 2.f * (t1v[j] - acc[j]) - t0[j];

  float outr[10], outi[10];
#pragma unroll
  for (int o = 0; o < 10; o++) { outr[o] = cb[o]; outi[o] = 0.f; }
#pragma unroll
  for (int i = 0; i < 10; i++) {
#pragma unroll
    for (int o = 0; o < 10; o++) {
      float w0 = cw[i * 10 + o], w1 = cw[100 + i * 10 + o], w2 = cw[200 + i * 10 + o];
      outr[o] += t0[i] * w0 + t1v[i] * w1 + t2[i] * w2;
      outi[o] += t0[10 + i] * w0 + t1v[10 + i] * w1 + t2[10 + i] * w2;
    }
  }
  float2* zrp = (float2*)(zr + (size_t)n * 10);
  float2* zip = (float2*)(zi + (size_t)n * 10);
#pragma unroll
  for (int q = 0; q < 5; q++) {
    zrp[q] = make_float2(fmaxf(outr[2 * q], 0.f), fmaxf(outr[2 * q + 1], 0.f));
    zip[q] = make_float2(fmaxf(outi[2 * q], 0.f), fmaxf(outi[2 * q + 1], 0.f));
  }
}

// ---------------- fc1 complex GEMM: split-bf16 MFMA (R8, unchanged) ----------------

__device__ __forceinline__ void cvt_hilo(float f, unsigned& h, unsigned& l) {
  unsigned u = __float_as_uint(f);
  h = (u + 0x7FFFu + ((u >> 16) & 1u)) >> 16;          // RNE to bf16
  float lf = f - __uint_as_float(h << 16);
  unsigned ul = __float_as_uint(lf);
  l = (ul + 0x7FFFu + ((ul >> 16) & 1u)) >> 16;
}

#define LIDX(a, r, c) (((a) * 64 + (r)) * LSTR + (c))

__global__ __launch_bounds__(256) void k_fc1(const float* __restrict__ zr, const float* __restrict__ zi,
                                             const float* __restrict__ Wr, const float* __restrict__ Wi,
                                             float* __restrict__ pacc) {
  __shared__ unsigned short ls[8 * 64 * LSTR];   // 0 zrh,1 zrl,2 zih,3 zil,4 wrh,5 wrl,6 wih,7 wil
  int t = threadIdx.x;
  int hb = blockIdx.x;          // 0..7
  int kc = blockIdx.y;          // 0..NKC-1
  int H0 = hb * 64;
  int lane = t & 63, wv = t >> 6;
  int m = lane & 15, q = lane >> 4;

  f32x4 p1[4], p2[4], p3[4], p4[4];
  f32x4 zero4 = {0.f, 0.f, 0.f, 0.f};
#pragma unroll
  for (int i = 0; i < 4; i++) { p1[i] = zero4; p2[i] = zero4; p3[i] = zero4; p4[i] = zero4; }

#pragma unroll 1
  for (int ks = 0; ks < KSTEPS; ks++) {
    int k0 = kc * CHUNK + ks * 32;
    __syncthreads();
#pragma unroll
    for (int p = 0; p < 8; p++) {
      int tau = t + (p << 8);
      int arr = tau >> 9;             // 0 zr, 1 zi, 2 Wr, 3 Wi
      int row = (tau >> 3) & 63;
      int grp = tau & 7;
      const float* base = (arr == 0) ? (zr + (size_t)row * K_)
                        : (arr == 1) ? (zi + (size_t)row * K_)
                        : (arr == 2) ? (Wr + (size_t)(H0 + row) * K_)
                                     : (Wi + (size_t)(H0 + row) * K_);
      float4 v = *(const float4*)(base + k0 + grp * 4);
      unsigned h0, l0, h1, l1, h2, l2, h3, l3;
      cvt_hilo(v.x, h0, l0); cvt_hilo(v.y, h1, l1);
      cvt_hilo(v.z, h2, l2); cvt_hilo(v.w, h3, l3);
      *(uint2*)&ls[LIDX(arr * 2,     row, grp * 4)] = make_uint2(h0 | (h1 << 16), h2 | (h3 << 16));
      *(uint2*)&ls[LIDX(arr * 2 + 1, row, grp * 4)] = make_uint2(l0 | (l1 << 16), l2 | (l3 << 16));
    }
    __syncthreads();

    short8 bwrh = *(const short8*)&ls[LIDX(4, wv * 16 + m, q * 8)];
    short8 bwrl = *(const short8*)&ls[LIDX(5, wv * 16 + m, q * 8)];
    short8 bwih = *(const short8*)&ls[LIDX(6, wv * 16 + m, q * 8)];
    short8 bwil = *(const short8*)&ls[LIDX(7, wv * 16 + m, q * 8)];
#pragma unroll
    for (int mt = 0; mt < 4; mt++) {
      short8 azrh = *(const short8*)&ls[LIDX(0, mt * 16 + m, q * 8)];
      short8 azrl = *(const short8*)&ls[LIDX(1, mt * 16 + m, q * 8)];
      short8 azih = *(const short8*)&ls[LIDX(2, mt * 16 + m, q * 8)];
      short8 azil = *(const short8*)&ls[LIDX(3, mt * 16 + m, q * 8)];
      p1[mt] = __builtin_amdgcn_mfma_f32_16x16x32_bf16(azrh, bwrh, p1[mt], 0, 0, 0);
      p2[mt] = __builtin_amdgcn_mfma_f32_16x16x32_bf16(azih, bwih, p2[mt], 0, 0, 0);
      p3[mt] = __builtin_amdgcn_mfma_f32_16x16x32_bf16(azrh, bwih, p3[mt], 0, 0, 0);
      p4[mt] = __builtin_amdgcn_mfma_f32_16x16x32_bf16(azih, bwrh, p4[mt], 0, 0, 0);
      p1[mt] = __builtin_amdgcn_mfma_f32_16x16x32_bf16(azrh, bwrl, p1[mt], 0, 0, 0);
      p2[mt] = __builtin_amdgcn_mfma_f32_16x16x32_bf16(azih, bwil, p2[mt], 0, 0, 0);
      p3[mt] = __builtin_amdgcn_mfma_f32_16x16x32_bf16(azrh, bwil, p3[mt], 0, 0, 0);
      p4[mt] = __builtin_amdgcn_mfma_f32_16x16x32_bf16(azih, bwrl, p4[mt], 0, 0, 0);
      p1[mt] = __builtin_amdgcn_mfma_f32_16x16x32_bf16(azrl, bwrh, p1[mt], 0, 0, 0);
      p2[mt] = __builtin_amdgcn_mfma_f32_16x16x32_bf16(azil, bwih, p2[mt], 0, 0, 0);
      p3[mt] = __builtin_amdgcn_mfma_f32_16x16x32_bf16(azrl, bwih, p3[mt], 0, 0, 0);
      p4[mt] = __builtin_amdgcn_mfma_f32_16x16x32_bf16(azil, bwrh, p4[mt], 0, 0, 0);
    }
  }

#pragma unroll
  for (int mt = 0; mt < 4; mt++) {
#pragma unroll
    for (int i = 0; i < 4; i++) {
      int b = mt * 16 + q * 4 + i;
      int h = H0 + wv * 16 + m;
      *(float2*)&pacc[(((size_t)kc * 64 + b) * 512 + h) * 2] =
          make_float2(p1[mt][i] - p2[mt][i], p3[mt][i] + p4[mt][i]);
    }
  }
}

// ---------------- reduce partials + fc1 bias/ReLU + actor/critic head ----------------

__global__ __launch_bounds__(256) void k_head(const float* __restrict__ pacc,
                                              const float* __restrict__ br, const float* __restrict__ bi,
                                              const float* __restrict__ actor_w, const float* __restrict__ actor_b,
                                              const float* __restrict__ critic_w, const float* __restrict__ critic_b,
                                              float* __restrict__ out) {
  __shared__ float urs[512], uis[512];
  int b = blockIdx.x, t = threadIdx.x;
  float s0r = 0, s0i = 0, s1r = 0, s1i = 0;
  for (int kc = 0; kc < NKC; kc++) {
    float4 v = *(const float4*)&pacc[(((size_t)kc * 64 + b) * 512 + 2 * t) * 2];
    s0r += v.x; s0i += v.y; s1r += v.z; s1i += v.w;
  }
  urs[2 * t]     = fmaxf(s0r + br[2 * t], 0.f);
  uis[2 * t]     = fmaxf(s0i + bi[2 * t], 0.f);
  urs[2 * t + 1] = fmaxf(s1r + br[2 * t + 1], 0.f);
  uis[2 * t + 1] = fmaxf(s1i + bi[2 * t + 1], 0.f);
  __syncthreads();
  if (t < 33) {
    const float* w = (t < 32) ? (actor_w + t * 1024) : critic_w;
    float acc = (t < 32) ? actor_b[t] : critic_b[0];
    for (int k = 0; k < 512; k++)
      acc += urs[k] * w[k] + uis[k] * w[512 + k];
    if (t < 32) out[b * 32 + t] = acc;
    else        out[2048 + b] = acc;
  }
}

// ---------------- launch ----------------

extern "C" void kernel_launch(void* const* d_in, const int* in_sizes, int n_in,
                              void* d_out, int out_size, void* d_ws, size_t ws_size,
                              hipStream_t stream) {
  const float* xr   = (const float*)d_in[0];
  const float* xi   = (const float*)d_in[1];
  const float* ew   = (const float*)d_in[2];
  const float* c1wr = (const float*)d_in[3];
  const float* c1wi = (const float*)d_in[4];
  const float* c1br = (const float*)d_in[5];
  const float* c1bi = (const float*)d_in[6];
  const float* chw  = (const float*)d_in[7];
  const float* chb  = (const float*)d_in[8];
  const float* f1wr = (const float*)d_in[9];
  const float* f1wi = (const float*)d_in[10];
  const float* f1br = (const float*)d_in[11];
  const float* f1bi = (const float*)d_in[12];
  const float* cw   = (const float*)d_in[13];
  const float* cb   = (const float*)d_in[14];
  const float* aw   = (const float*)d_in[15];
  const float* ab   = (const float*)d_in[16];
  const int*   ei   = (const int*)d_in[17];
  float* out = (float*)d_out;

  char* ws = (char*)d_ws;
  size_t off = 0;
  auto alloc = [&](size_t bytes) { char* p = ws + off; off += (bytes + 255) & ~(size_t)255; return p; };
  int*   cnt      = (int*)  alloc((size_t)NN_ * 4);
  int*   rowstart = (int*)  alloc((size_t)NN_ * 4);
  float* dinv     = (float*)alloc((size_t)NN_ * 4);
  int*   bsum     = (int*)  alloc(1024);
  int*   boff     = (int*)  alloc(1024);
  float* zr       = (float*)alloc((size_t)NN_ * 10 * 4);
  float* zi       = (float*)alloc((size_t)NN_ * 10 * 4);
  int2*  ecsr     = (int2*) alloc((size_t)E_ * 8);    // dead after lap2cheb
  float* Y        = (float*)alloc((size_t)NN_ * 20 * 4);
  float* T1       = (float*)alloc((size_t)NN_ * 20 * 4);
  // pack8 (8 MB, dead after k_off) aliases Y (10.5 MB, born at conv1)
  unsigned long long* pack8 = (unsigned long long*)Y;
  // ord (4 MB) + so (1 MB), dead after k_build, alias T1 (10.5 MB, born at lap1)
  unsigned short*     ord   = (unsigned short*)T1;
  unsigned long long* so    = (unsigned long long*)((char*)T1 + (size_t)E_ * 2);
  // pacc (33.5 MB, born at fc1) aliases ecsr+Y+T1 (37.8 MB, all dead by then)
  float* pacc = (float*)ecsr;

  hipMemsetAsync(pack8, 0, (size_t)8 * NN_ * 8, stream);

  k_cnt<<<E_ / 256, 256, 0, stream>>>(ei, ew, pack8, ord);
  k_off<<<NN_ / 256, 256, 0, stream>>>(pack8, cnt, dinv, so);
  k_scan_a<<<256, 256, 0, stream>>>(cnt, bsum);
  k_scan_b<<<1, 256, 0, stream>>>(bsum, boff);
  k_scan_c<<<256, 256, 0, stream>>>(cnt, boff, rowstart);
  k_build<<<E_ / 256, 256, 0, stream>>>(ei, ew, dinv, rowstart, ord, so, ecsr);
  k_conv1<<<NN_ / 256, 256, 0, stream>>>(xr, xi, c1wr, c1wi, c1br, c1bi, Y);
  k_lap1<<<NN_ / 256, 256, 0, stream>>>(Y, ecsr, rowstart, cnt, T1);
  k_lap2cheb<<<NN_ / 256, 256, 0, stream>>>(Y, T1, ecsr, rowstart, cnt, chw, chb, zr, zi);
  k_fc1<<<dim3(8, NKC), 256, 0, stream>>>(zr, zi, f1wr, f1wi, pacc);
  k_head<<<B_, 256, 0, stream>>>(pacc, f1br, f1bi, aw, ab, cw, cb, out);
}

// Round 10
// 477.262 us; speedup vs baseline: 1.7913x; 1.1311x over previous
//
#include <hip/hip_runtime.h>

#define NN_ 131072
#define E_  2097152
#define B_  64
#define K_  20480
#define H_  512
#define EPS_ 1e-6f
#define DEGSCALE 4194304.0f      // 2^22
#define DEGINV   (1.0f / 4194304.0f)
#define NKC 128                  // fc1 K-split chunks
#define CHUNK 160                // K_ / NKC
#define KSTEPS 5                 // CHUNK / 32 (MFMA k=32 per step)
#define LSTR 40                  // fc1 LDS row stride in bf16 elems
#define NB 1024                  // CSR buckets
#define RPB 128                  // rows per bucket (NN/NB)
#define EB 2048                  // edges per p1 block
#define P1B (E_ / EB)            // 1024 p1 blocks

typedef __attribute__((ext_vector_type(8))) short short8;   // 8 bf16 (4 VGPRs)
typedef __attribute__((ext_vector_type(4))) float f32x4;    // MFMA accumulator

// ---------------- graph preprocessing: bucket-sort CSR, ZERO global atomics ----
// R10: global atomics write through to HBM (~21 G/s ceiling, measured R4-R9)
// regardless of scope/width. Replaced with 2-level bucket sort: LDS histograms
// + scans + plain scattered stores (L2 write-back merges them).

__global__ __launch_bounds__(256) void k_p1hist(const int* __restrict__ ei, int* __restrict__ blockhist) {
  __shared__ int h[NB];
  int t = threadIdx.x, blk = blockIdx.x;
  for (int i = t; i < NB; i += 256) h[i] = 0;
  __syncthreads();
  int e0 = blk * EB;
#pragma unroll
  for (int i = 0; i < EB / 256; i++) {
    int r = ei[e0 + i * 256 + t];
    atomicAdd(&h[r >> 7], 1);
  }
  __syncthreads();
  for (int i = t; i < NB; i += 256) blockhist[blk * NB + i] = h[i];
}

// per-bucket exclusive scan over the 1024 block counts (in place) + bucket totals
__global__ __launch_bounds__(256) void k_p1scanA(int* __restrict__ blockhist, int* __restrict__ btot) {
  __shared__ int s[256];
  int t = threadIdx.x, b = blockIdx.x;
  int v[4], sum = 0;
#pragma unroll
  for (int j = 0; j < 4; j++) { v[j] = blockhist[(4 * t + j) * NB + b]; sum += v[j]; }
  s[t] = sum;
  __syncthreads();
  for (int off = 1; off < 256; off <<= 1) {
    int x = (t >= off) ? s[t - off] : 0;
    __syncthreads();
    s[t] += x;
    __syncthreads();
  }
  int o = s[t] - sum;
#pragma unroll
  for (int j = 0; j < 4; j++) { blockhist[(4 * t + j) * NB + b] = o; o += v[j]; }
  if (t == 0) btot[b] = s[255];
}

// exclusive scan of 1024 bucket totals -> bstart[0..NB], bstart[NB]=E
__global__ __launch_bounds__(256) void k_p1scanB(const int* __restrict__ btot, int* __restrict__ bstart) {
  __shared__ int s[256];
  int t = threadIdx.x;
  int v[4], sum = 0;
#pragma unroll
  for (int j = 0; j < 4; j++) { v[j] = btot[4 * t + j]; sum += v[j]; }
  s[t] = sum;
  __syncthreads();
  for (int off = 1; off < 256; off <<= 1) {
    int x = (t >= off) ? s[t - off] : 0;
    __syncthreads();
    s[t] += x;
    __syncthreads();
  }
  int o = s[t] - sum;
#pragma unroll
  for (int j = 0; j < 4; j++) { bstart[4 * t + j] = o; o += v[j]; }
  if (t == 0) bstart[NB] = s[255];
}

// scatter (col, ew) + local-row records into bucket regions (plain stores)
__global__ __launch_bounds__(256) void k_p1scat(const int* __restrict__ ei, const float* __restrict__ ew,
                                                const int* __restrict__ blockhist, const int* __restrict__ bstart,
                                                int2* __restrict__ recA, unsigned short* __restrict__ recR) {
  __shared__ int run[NB], base[NB];
  int t = threadIdx.x, blk = blockIdx.x;
  for (int i = t; i < NB; i += 256) {
    run[i] = 0;
    base[i] = bstart[i] + blockhist[blk * NB + i];
  }
  __syncthreads();
  int e0 = blk * EB;
#pragma unroll
  for (int i = 0; i < EB / 256; i++) {
    int e = e0 + i * 256 + t;
    int r = ei[e], c = ei[E_ + e];
    float w = ew[e];
    int bkt = r >> 7;
    int pos = base[bkt] + atomicAdd(&run[bkt], 1);
    recA[pos] = make_int2(c, __float_as_int(w));
    recR[pos] = (unsigned short)(r & 127);
  }
}

// per-bucket: count + Q22 deg -> dinv/cnt/rowstart; then build ecsr (w = ew*dinv[r])
__global__ __launch_bounds__(256) void k_p2(const int2* __restrict__ recA, const unsigned short* __restrict__ recR,
                                            const int* __restrict__ bstart,
                                            int* __restrict__ cnt_g, int* __restrict__ rowstart,
                                            float* __restrict__ dinv, int2* __restrict__ ecsr) {
  __shared__ int cnt_s[RPB], excl_s[RPB], run_s[RPB], sc[RPB];
  __shared__ unsigned deg_s[RPB];
  __shared__ float dl[RPB];
  int t = threadIdx.x, b = blockIdx.x;
  int b0 = bstart[b], nE = bstart[b + 1] - b0;
  if (t < RPB) { cnt_s[t] = 0; deg_s[t] = 0; run_s[t] = 0; }
  __syncthreads();
  for (int i = t; i < nE; i += 256) {
    int lr = recR[b0 + i];
    float w = __int_as_float(recA[b0 + i].y);
    atomicAdd(&cnt_s[lr], 1);
    atomicAdd(&deg_s[lr], (unsigned)(w * DEGSCALE + 0.5f));
  }
  __syncthreads();
  if (t < RPB) sc[t] = cnt_s[t];
  __syncthreads();
  for (int off = 1; off < RPB; off <<= 1) {
    int x = (t < RPB && t >= off) ? sc[t - off] : 0;
    __syncthreads();
    if (t < RPB) sc[t] += x;
    __syncthreads();
  }
  if (t < RPB) {
    int excl = sc[t] - cnt_s[t];
    excl_s[t] = excl;
    int row = b * RPB + t;
    rowstart[row] = b0 + excl;
    cnt_g[row] = cnt_s[t];
    float d = (float)deg_s[t] * DEGINV;
    float dv = (d > 0.f) ? rsqrtf(d + EPS_) : 0.f;
    dl[t] = dv;
    dinv[row] = dv;
  }
  __syncthreads();
  for (int i = t; i < nE; i += 256) {
    int lr = recR[b0 + i];
    int2 ra = recA[b0 + i];
    int pos = excl_s[lr] + atomicAdd(&run_s[lr], 1);
    float wp = __int_as_float(ra.y) * dl[lr];
    ecsr[b0 + pos] = make_int2(ra.x, __float_as_int(wp));
  }
}

// finalize w *= dinv[col]  (keeps lap kernels unchanged)
__global__ __launch_bounds__(256) void k_wfix(int2* __restrict__ ecsr, const float* __restrict__ dinv) {
  int e = blockIdx.x * 256 + threadIdx.x;
  if (e >= E_) return;
  int2 r = ecsr[e];
  r.y = __float_as_int(__int_as_float(r.y) * dinv[r.x]);
  ecsr[e] = r;
}

// ---------------- conv1 (complex 1x1 conv + ReLU) ----------------
// Y layout: [NN][20]  (0..9 real, 10..19 imag)

__global__ __launch_bounds__(256) void k_conv1(const float* __restrict__ xr, const float* __restrict__ xi,
                                               const float* __restrict__ wr_g, const float* __restrict__ wi_g,
                                               const float* __restrict__ br_g, const float* __restrict__ bi_g,
                                               float* __restrict__ Y) {
  __shared__ float wr[100], wi[100], br[10], bi[10];
  int t = threadIdx.x;
  if (t < 100) { wr[t] = wr_g[t]; wi[t] = wi_g[t]; }
  if (t < 10)  { br[t] = br_g[t]; bi[t] = bi_g[t]; }
  __syncthreads();
  int n = blockIdx.x * 256 + t;
  float xrv[10], xiv[10];
  const float2* a = (const float2*)(xr + (size_t)n * 10);
  const float2* b2 = (const float2*)(xi + (size_t)n * 10);
#pragma unroll
  for (int i = 0; i < 5; i++) {
    float2 v = a[i];  xrv[2 * i] = v.x; xrv[2 * i + 1] = v.y;
    float2 u = b2[i]; xiv[2 * i] = u.x; xiv[2 * i + 1] = u.y;
  }
  float out[20];
#pragma unroll
  for (int c = 0; c < 10; c++) {
    float ar = br[c], ai = bi[c];
#pragma unroll
    for (int tt = 0; tt < 10; tt++) {
      float wrc = wr[c * 10 + tt], wic = wi[c * 10 + tt];
      ar += xrv[tt] * wrc - xiv[tt] * wic;
      ai += xrv[tt] * wic + xiv[tt] * wrc;
    }
    out[c] = fmaxf(ar, 0.f);
    out[10 + c] = fmaxf(ai, 0.f);
  }
  float4* yp = (float4*)(Y + (size_t)n * 20);
#pragma unroll
  for (int i = 0; i < 5; i++)
    yp[i] = make_float4(out[4 * i], out[4 * i + 1], out[4 * i + 2], out[4 * i + 3]);
}

// ---------------- Laplacian pass 1: T1 = Y - S(Y) ----------------

__global__ __launch_bounds__(256) void k_lap1(const float* __restrict__ Y, const int2* __restrict__ ecsr,
                                              const int* __restrict__ rowstart,
                                              const int* __restrict__ cnt, float* __restrict__ T1) {
  int n = blockIdx.x * 256 + threadIdx.x;
  float acc[20];
#pragma unroll
  for (int j = 0; j < 20; j++) acc[j] = 0.f;
  int e0 = rowstart[n], ec = cnt[n];
  for (int i = 0; i < ec; i++) {
    int2 rec = ecsr[e0 + i];
    int c = rec.x;
    float w = __int_as_float(rec.y);
    const float4* yp = (const float4*)(Y + (size_t)c * 20);
#pragma unroll
    for (int q = 0; q < 5; q++) {
      float4 v = yp[q];
      acc[4 * q]     += w * v.x;
      acc[4 * q + 1] += w * v.y;
      acc[4 * q + 2] += w * v.z;
      acc[4 * q + 3] += w * v.w;
    }
  }
  const float4* yn = (const float4*)(Y + (size_t)n * 20);
  float4* tp = (float4*)(T1 + (size_t)n * 20);
#pragma unroll
  for (int q = 0; q < 5; q++) {
    float4 v = yn[q];
    tp[q] = make_float4(v.x - acc[4 * q], v.y - acc[4 * q + 1],
                        v.z - acc[4 * q + 2], v.w - acc[4 * q + 3]);
  }
}

// ---------------- Laplacian pass 2 + Chebyshev combine + ReLU ----------------

__global__ __launch_bounds__(256) void k_lap2cheb(const float* __restrict__ Y, const float* __restrict__ T1,
                                                  const int2* __restrict__ ecsr,
                                                  const int* __restrict__ rowstart, const int* __restrict__ cnt,
                                                  const float* __restrict__ cw_g, const float* __restrict__ cb_g,
                                                  float* __restrict__ zr, float* __restrict__ zi) {
  __shared__ float cw[300], cb[10];
  int t = threadIdx.x;
  for (int j = t; j < 300; j += 256) cw[j] = cw_g[j];
  if (t < 10)  cb[t] = cb_g[t];
  __syncthreads();
  int n = blockIdx.x * 256 + t;
  float acc[20];
#pragma unroll
  for (int j = 0; j < 20; j++) acc[j] = 0.f;
  int e0 = rowstart[n], ec = cnt[n];
  for (int i = 0; i < ec; i++) {
    int2 rec = ecsr[e0 + i];
    int c = rec.x;
    float w = __int_as_float(rec.y);
    const float4* tp = (const float4*)(T1 + (size_t)c * 20);
#pragma unroll
    for (int q = 0; q < 5; q++) {
      float4 v = tp[q];
      acc[4 * q]     += w * v.x;
      acc[4 * q + 1] += w * v.y;
      acc[4 * q + 2] += w * v.z;
      acc[4 * q + 3] += w * v.w;
    }
  }
  float t0[20], t1v[20], t2[20];
  const float4* yn = (const float4*)(Y + (size_t)n * 20);
  const float4* tn = (const float4*)(T1 + (size_t)n * 20);
#pragma unroll
  for (int q = 0; q < 5; q++) {
    float4 v = yn[q]; t0[4 * q] = v.x; t0[4 * q + 1] = v.y; t0[4 * q + 2] = v.z; t0[4 * q + 3] = v.w;
    float4 u = tn[q]; t1v[4 * q] = u.x; t1v[4 * q + 1] = u.y; t1v[4 * q + 2] = u.z; t1v[4 * q + 3] = u.w;
  }
#pragma unroll
  for (int j = 0; j < 20; j++) t2[j] = 2.f * (t1v[j] - acc[j]) - t0[j];

  float outr[10], outi[10];
#pragma unroll
  for (int o = 0; o < 10; o++) { outr[o] = cb[o]; outi[o] = 0.f; }
#pragma unroll
  for (int i = 0; i < 10; i++) {
#pragma unroll
    for (int o = 0; o < 10; o++) {
      float w0 = cw[i * 10 + o], w1 = cw[100 + i * 10 + o], w2 = cw[200 + i * 10 + o];
      outr[o] += t0[i] * w0 + t1v[i] * w1 + t2[i] * w2;
      outi[o] += t0[10 + i] * w0 + t1v[10 + i] * w1 + t2[10 + i] * w2;
    }
  }
  float2* zrp = (float2*)(zr + (size_t)n * 10);
  float2* zip = (float2*)(zi + (size_t)n * 10);
#pragma unroll
  for (int q = 0; q < 5; q++) {
    zrp[q] = make_float2(fmaxf(outr[2 * q], 0.f), fmaxf(outr[2 * q + 1], 0.f));
    zip[q] = make_float2(fmaxf(outi[2 * q], 0.f), fmaxf(outi[2 * q + 1], 0.f));
  }
}

// ---------------- fc1 complex GEMM: split-bf16 MFMA (R8, unchanged) ----------------

__device__ __forceinline__ void cvt_hilo(float f, unsigned& h, unsigned& l) {
  unsigned u = __float_as_uint(f);
  h = (u + 0x7FFFu + ((u >> 16) & 1u)) >> 16;          // RNE to bf16
  float lf = f - __uint_as_float(h << 16);
  unsigned ul = __float_as_uint(lf);
  l = (ul + 0x7FFFu + ((ul >> 16) & 1u)) >> 16;
}

#define LIDX(a, r, c) (((a) * 64 + (r)) * LSTR + (c))

__global__ __launch_bounds__(256) void k_fc1(const float* __restrict__ zr, const float* __restrict__ zi,
                                             const float* __restrict__ Wr, const float* __restrict__ Wi,
                                             float* __restrict__ pacc) {
  __shared__ unsigned short ls[8 * 64 * LSTR];   // 0 zrh,1 zrl,2 zih,3 zil,4 wrh,5 wrl,6 wih,7 wil
  int t = threadIdx.x;
  int hb = blockIdx.x;          // 0..7
  int kc = blockIdx.y;          // 0..NKC-1
  int H0 = hb * 64;
  int lane = t & 63, wv = t >> 6;
  int m = lane & 15, q = lane >> 4;

  f32x4 p1[4], p2[4], p3[4], p4[4];
  f32x4 zero4 = {0.f, 0.f, 0.f, 0.f};
#pragma unroll
  for (int i = 0; i < 4; i++) { p1[i] = zero4; p2[i] = zero4; p3[i] = zero4; p4[i] = zero4; }

#pragma unroll 1
  for (int ks = 0; ks < KSTEPS; ks++) {
    int k0 = kc * CHUNK + ks * 32;
    __syncthreads();
#pragma unroll
    for (int p = 0; p < 8; p++) {
      int tau = t + (p << 8);
      int arr = tau >> 9;             // 0 zr, 1 zi, 2 Wr, 3 Wi
      int row = (tau >> 3) & 63;
      int grp = tau & 7;
      const float* base = (arr == 0) ? (zr + (size_t)row * K_)
                        : (arr == 1) ? (zi + (size_t)row * K_)
                        : (arr == 2) ? (Wr + (size_t)(H0 + row) * K_)
                                     : (Wi + (size_t)(H0 + row) * K_);
      float4 v = *(const float4*)(base + k0 + grp * 4);
      unsigned h0, l0, h1, l1, h2, l2, h3, l3;
      cvt_hilo(v.x, h0, l0); cvt_hilo(v.y, h1, l1);
      cvt_hilo(v.z, h2, l2); cvt_hilo(v.w, h3, l3);
      *(uint2*)&ls[LIDX(arr * 2,     row, grp * 4)] = make_uint2(h0 | (h1 << 16), h2 | (h3 << 16));
      *(uint2*)&ls[LIDX(arr * 2 + 1, row, grp * 4)] = make_uint2(l0 | (l1 << 16), l2 | (l3 << 16));
    }
    __syncthreads();

    short8 bwrh = *(const short8*)&ls[LIDX(4, wv * 16 + m, q * 8)];
    short8 bwrl = *(const short8*)&ls[LIDX(5, wv * 16 + m, q * 8)];
    short8 bwih = *(const short8*)&ls[LIDX(6, wv * 16 + m, q * 8)];
    short8 bwil = *(const short8*)&ls[LIDX(7, wv * 16 + m, q * 8)];
#pragma unroll
    for (int mt = 0; mt < 4; mt++) {
      short8 azrh = *(const short8*)&ls[LIDX(0, mt * 16 + m, q * 8)];
      short8 azrl = *(const short8*)&ls[LIDX(1, mt * 16 + m, q * 8)];
      short8 azih = *(const short8*)&ls[LIDX(2, mt * 16 + m, q * 8)];
      short8 azil = *(const short8*)&ls[LIDX(3, mt * 16 + m, q * 8)];
      p1[mt] = __builtin_amdgcn_mfma_f32_16x16x32_bf16(azrh, bwrh, p1[mt], 0, 0, 0);
      p2[mt] = __builtin_amdgcn_mfma_f32_16x16x32_bf16(azih, bwih, p2[mt], 0, 0, 0);
      p3[mt] = __builtin_amdgcn_mfma_f32_16x16x32_bf16(azrh, bwih, p3[mt], 0, 0, 0);
      p4[mt] = __builtin_amdgcn_mfma_f32_16x16x32_bf16(azih, bwrh, p4[mt], 0, 0, 0);
      p1[mt] = __builtin_amdgcn_mfma_f32_16x16x32_bf16(azrh, bwrl, p1[mt], 0, 0, 0);
      p2[mt] = __builtin_amdgcn_mfma_f32_16x16x32_bf16(azih, bwil, p2[mt], 0, 0, 0);
      p3[mt] = __builtin_amdgcn_mfma_f32_16x16x32_bf16(azrh, bwil, p3[mt], 0, 0, 0);
      p4[mt] = __builtin_amdgcn_mfma_f32_16x16x32_bf16(azih, bwrl, p4[mt], 0, 0, 0);
      p1[mt] = __builtin_amdgcn_mfma_f32_16x16x32_bf16(azrl, bwrh, p1[mt], 0, 0, 0);
      p2[mt] = __builtin_amdgcn_mfma_f32_16x16x32_bf16(azil, bwih, p2[mt], 0, 0, 0);
      p3[mt] = __builtin_amdgcn_mfma_f32_16x16x32_bf16(azrl, bwih, p3[mt], 0, 0, 0);
      p4[mt] = __builtin_amdgcn_mfma_f32_16x16x32_bf16(azil, bwrh, p4[mt], 0, 0, 0);
    }
  }

#pragma unroll
  for (int mt = 0; mt < 4; mt++) {
#pragma unroll
    for (int i = 0; i < 4; i++) {
      int b = mt * 16 + q * 4 + i;
      int h = H0 + wv * 16 + m;
      *(float2*)&pacc[(((size_t)kc * 64 + b) * 512 + h) * 2] =
          make_float2(p1[mt][i] - p2[mt][i], p3[mt][i] + p4[mt][i]);
    }
  }
}

// ---------------- reduce partials + fc1 bias/ReLU + actor/critic head ----------------

__global__ __launch_bounds__(256) void k_head(const float* __restrict__ pacc,
                                              const float* __restrict__ br, const float* __restrict__ bi,
                                              const float* __restrict__ actor_w, const float* __restrict__ actor_b,
                                              const float* __restrict__ critic_w, const float* __restrict__ critic_b,
                                              float* __restrict__ out) {
  __shared__ float urs[512], uis[512];
  int b = blockIdx.x, t = threadIdx.x;
  float s0r = 0, s0i = 0, s1r = 0, s1i = 0;
  for (int kc = 0; kc < NKC; kc++) {
    float4 v = *(const float4*)&pacc[(((size_t)kc * 64 + b) * 512 + 2 * t) * 2];
    s0r += v.x; s0i += v.y; s1r += v.z; s1i += v.w;
  }
  urs[2 * t]     = fmaxf(s0r + br[2 * t], 0.f);
  uis[2 * t]     = fmaxf(s0i + bi[2 * t], 0.f);
  urs[2 * t + 1] = fmaxf(s1r + br[2 * t + 1], 0.f);
  uis[2 * t + 1] = fmaxf(s1i + bi[2 * t + 1], 0.f);
  __syncthreads();
  if (t < 33) {
    const float* w = (t < 32) ? (actor_w + t * 1024) : critic_w;
    float acc = (t < 32) ? actor_b[t] : critic_b[0];
    for (int k = 0; k < 512; k++)
      acc += urs[k] * w[k] + uis[k] * w[512 + k];
    if (t < 32) out[b * 32 + t] = acc;
    else        out[2048 + b] = acc;
  }
}

// ---------------- launch ----------------

extern "C" void kernel_launch(void* const* d_in, const int* in_sizes, int n_in,
                              void* d_out, int out_size, void* d_ws, size_t ws_size,
                              hipStream_t stream) {
  const float* xr   = (const float*)d_in[0];
  const float* xi   = (const float*)d_in[1];
  const float* ew   = (const float*)d_in[2];
  const float* c1wr = (const float*)d_in[3];
  const float* c1wi = (const float*)d_in[4];
  const float* c1br = (const float*)d_in[5];
  const float* c1bi = (const float*)d_in[6];
  const float* chw  = (const float*)d_in[7];
  const float* chb  = (const float*)d_in[8];
  const float* f1wr = (const float*)d_in[9];
  const float* f1wi = (const float*)d_in[10];
  const float* f1br = (const float*)d_in[11];
  const float* f1bi = (const float*)d_in[12];
  const float* cw   = (const float*)d_in[13];
  const float* cb   = (const float*)d_in[14];
  const float* aw   = (const float*)d_in[15];
  const float* ab   = (const float*)d_in[16];
  const int*   ei   = (const int*)d_in[17];
  float* out = (float*)d_out;

  char* ws = (char*)d_ws;
  size_t off = 0;
  auto alloc = [&](size_t bytes) { char* p = ws + off; off += (bytes + 255) & ~(size_t)255; return p; };
  int*   cnt      = (int*)  alloc((size_t)NN_ * 4);
  int*   rowstart = (int*)  alloc((size_t)NN_ * 4);
  float* dinv     = (float*)alloc((size_t)NN_ * 4);
  int*   btot     = (int*)  alloc((size_t)NB * 4);
  int*   bstart   = (int*)  alloc((size_t)(NB + 1) * 4);
  float* zr       = (float*)alloc((size_t)NN_ * 10 * 4);
  float* zi       = (float*)alloc((size_t)NN_ * 10 * 4);
  int2*  ecsr     = (int2*) alloc((size_t)E_ * 8);    // born at k_p2; dead after lap2cheb
  float* Y        = (float*)alloc((size_t)NN_ * 20 * 4);   // born at conv1
  float* T1       = (float*)alloc((size_t)NN_ * 20 * 4);   // born at lap1 (contiguous after Y)
  // blockhist (4 MB, dead after p1scat) aliases ecsr head (ecsr born at k_p2)
  int* blockhist = (int*)ecsr;
  // recA (16 MB) + recR (4 MB), dead after k_p2, alias Y+T1 (contiguous 21 MB)
  int2*           recA = (int2*)Y;
  unsigned short* recR = (unsigned short*)((char*)Y + (size_t)E_ * 8);
  // pacc (33.5 MB, born at fc1) aliases ecsr+Y+T1 (37.8 MB, all dead by then)
  float* pacc = (float*)ecsr;

  k_p1hist<<<P1B, 256, 0, stream>>>(ei, blockhist);
  k_p1scanA<<<NB, 256, 0, stream>>>(blockhist, btot);
  k_p1scanB<<<1, 256, 0, stream>>>(btot, bstart);
  k_p1scat<<<P1B, 256, 0, stream>>>(ei, ew, blockhist, bstart, recA, recR);
  k_p2<<<NB, 256, 0, stream>>>(recA, recR, bstart, cnt, rowstart, dinv, ecsr);
  k_wfix<<<E_ / 256, 256, 0, stream>>>(ecsr, dinv);
  k_conv1<<<NN_ / 256, 256, 0, stream>>>(xr, xi, c1wr, c1wi, c1br, c1bi, Y);
  k_lap1<<<NN_ / 256, 256, 0, stream>>>(Y, ecsr, rowstart, cnt, T1);
  k_lap2cheb<<<NN_ / 256, 256, 0, stream>>>(Y, T1, ecsr, rowstart, cnt, chw, chb, zr, zi);
  k_fc1<<<dim3(8, NKC), 256, 0, stream>>>(zr, zi, f1wr, f1wi, pacc);
  k_head<<<B_, 256, 0, stream>>>(pacc, f1br, f1bi, aw, ab, cw, cb, out);
}